// Round 11
// baseline (392.282 us; speedup 1.0000x reference)
//
#include <hip/hip_runtime.h>
#include <math.h>

#define DIN  128
#define HC   128
#define NEG  0.2f

typedef __attribute__((ext_vector_type(8))) short bf16x8;
typedef __attribute__((ext_vector_type(4))) float f32x4;
typedef __attribute__((ext_vector_type(8))) _Float16 half8;

__device__ __forceinline__ unsigned short f2bf_rne(float x) {
    unsigned u = __float_as_uint(x);
    unsigned r = u + 0x7FFFu + ((u >> 16) & 1u);
    return (unsigned short)(r >> 16);
}
__device__ __forceinline__ float bf2f(unsigned short h) {
    return __uint_as_float(((unsigned)h) << 16);
}

// 16-lane (DPP-row) butterfly sum: xor1, xor2, xor7, xor15 — pure VALU.
template <int CTRL>
__device__ __forceinline__ float dpp_xadd(float x) {
    int r = __builtin_amdgcn_update_dpp(0, __float_as_int(x), CTRL, 0xF, 0xF, true);
    return x + __int_as_float(r);
}
__device__ __forceinline__ float rowsum16(float x) {
    x = dpp_xadd<0xB1>(x);   // lane ^ 1
    x = dpp_xadd<0x4E>(x);   // lane ^ 2
    x = dpp_xadd<0x141>(x);  // lane ^ 7
    x = dpp_xadd<0x140>(x);  // lane ^ 15
    return x;
}

// ---------------------------------------------------------------------------
// CSR build
// ---------------------------------------------------------------------------
__global__ void hist_kernel(const int* __restrict__ ei, int E, int N,
                            int* __restrict__ counts) {
    int i = blockIdx.x * blockDim.x + threadIdx.x;
    int Etot = E + N;
    if (i >= Etot) return;
    int dst = (i < E) ? ei[E + i] : (i - E);
    if (dst < 0 || dst >= N) return;
    atomicAdd(&counts[dst], 1);
}

__global__ void scan_kernel(const int* __restrict__ counts,
                            int* __restrict__ rowptr,
                            int* __restrict__ cursor, int n) {
    __shared__ int wsum[16];
    int tid  = threadIdx.x;          // 1024 threads
    int lane = tid & 63, wid = tid >> 6;
    int running = 0;
    for (int base = 0; base < n; base += 4096) {
        int i = base + tid * 4;
        int4 v = make_int4(0, 0, 0, 0);
        if (i < n) v = *(const int4*)&counts[i];   // n % 4 == 0
        int ssum = v.x + v.y + v.z + v.w;
        int x = ssum;
        #pragma unroll
        for (int off = 1; off < 64; off <<= 1) {
            int y = __shfl_up(x, off, 64);
            if (lane >= off) x += y;
        }
        if (lane == 63) wsum[wid] = x;
        __syncthreads();
        if (tid < 16) {
            int w = wsum[tid];
            #pragma unroll
            for (int off = 1; off < 16; off <<= 1) {
                int y = __shfl_up(w, off, 64);
                if (tid >= off) w += y;
            }
            wsum[tid] = w;
        }
        __syncthreads();
        int excl = running + (wid ? wsum[wid - 1] : 0) + (x - ssum);
        if (i < n) {
            int4 r;
            r.x = excl;
            r.y = r.x + v.x;
            r.z = r.y + v.y;
            r.w = r.z + v.z;
            *(int4*)&rowptr[i] = r;
            *(int4*)&cursor[i] = r;
        }
        running += wsum[15];
        __syncthreads();
    }
    if (tid == 0) rowptr[n] = running;
}

__global__ void scatter_kernel(const int* __restrict__ ei, int E, int N,
                               int* __restrict__ cursor,
                               int* __restrict__ esrc) {
    int i = blockIdx.x * blockDim.x + threadIdx.x;
    int Etot = E + N;
    if (i >= Etot) return;
    int src = (i < E) ? ei[i]     : (i - E);
    int dst = (i < E) ? ei[E + i] : (i - E);
    if (dst < 0 || dst >= N || src < 0 || src >= N) return;
    int pos = atomicAdd(&cursor[dst], 1);
    esrc[pos] = src;
}

// ---------------------------------------------------------------------------
// W prep: split each 128x128 W into bf16 hi/lo, packed in MFMA B-fragment
// order: slot (kb,nf,lane,j) = W[kb*32 + (lane>>4)*8 + j][nf*16 + (lane&15)].
// ---------------------------------------------------------------------------
__global__ __launch_bounds__(256) void prep_w(
        const float* __restrict__ W1l, const float* __restrict__ W1r,
        const float* __restrict__ W2l, const float* __restrict__ W2r,
        const float* __restrict__ W3l, const float* __restrict__ W3r,
        unsigned short* __restrict__ hi, unsigned short* __restrict__ lo) {
    int m = blockIdx.y;
    const float* W = (m == 0) ? W1l : (m == 1) ? W1r : (m == 2) ? W2l
                   : (m == 3) ? W2r : (m == 4) ? W3l : W3r;
    int t = blockIdx.x * 256 + threadIdx.x;    // 0..2047 (grid.x = 8)
    int kb = t >> 9, nf = (t >> 6) & 7, l = t & 63;
    int col = nf * 16 + (l & 15);
    int k0  = kb * 32 + (l >> 4) * 8;
    size_t ob = ((size_t)m * 2048 + t) * 8;
    #pragma unroll
    for (int j = 0; j < 8; ++j) {
        float v = W[(size_t)(k0 + j) * 128 + col];
        unsigned short h = f2bf_rne(v);
        hi[ob + j] = h;
        lo[ob + j] = f2bf_rne(v - bf2f(h));
    }
}

// ---------------------------------------------------------------------------
// Dual MFMA GEMM (split-bf16, 3 terms). Outputs stored FP16 in the
// INTERLEAVED per-lane layout consumed by gat_aggregate:
//   newpos(col) = (4*(nf&3) + (m15>>2))*8 + (nf>>2)*4 + (m15&3)
// so lane gl's 8 channels {head0:4gl..4gl+3, head1:64+4gl..} are contiguous
// 16 bytes — one gather per edge instead of two.
// ---------------------------------------------------------------------------
__global__ __launch_bounds__(256) void gemm_mfma_dual(
        const float* __restrict__ X,
        const unsigned short* __restrict__ Whi,
        const unsigned short* __restrict__ Wlo, int matbase,
        const float* __restrict__ bl, const float* __restrict__ br,
        _Float16* __restrict__ xlh, _Float16* __restrict__ xrh, int nrows) {
    const unsigned short* hpl = Whi + ((size_t)(matbase + 0) * 16384);
    const unsigned short* lpl = Wlo + ((size_t)(matbase + 0) * 16384);
    const unsigned short* hpr = Whi + ((size_t)(matbase + 1) * 16384);
    const unsigned short* lpr = Wlo + ((size_t)(matbase + 1) * 16384);

    int w   = threadIdx.x >> 6;
    int l   = threadIdx.x & 63;
    int m15 = l & 15, g = l >> 4;
    int rowbase = blockIdx.x * 64 + w * 16;

    f32x4 accl[8], accr[8];
    #pragma unroll
    for (int nf = 0; nf < 8; ++nf) {
        accl[nf] = (f32x4){0.f, 0.f, 0.f, 0.f};
        accr[nf] = (f32x4){0.f, 0.f, 0.f, 0.f};
    }

    #pragma unroll
    for (int kb = 0; kb < 4; ++kb) {
        int arow = rowbase + m15;
        float4 x0 = make_float4(0.f, 0.f, 0.f, 0.f), x1 = x0;
        if (arow < nrows) {
            const float* xp = &X[(size_t)arow * 128 + kb * 32 + g * 8];
            x0 = *(const float4*)xp;
            x1 = *(const float4*)(xp + 4);
        }
        float xv[8] = {x0.x, x0.y, x0.z, x0.w, x1.x, x1.y, x1.z, x1.w};
        bf16x8 ahi, alo;
        #pragma unroll
        for (int j = 0; j < 8; ++j) {
            unsigned short h = f2bf_rne(xv[j]);
            ahi[j] = (short)h;
            alo[j] = (short)f2bf_rne(xv[j] - bf2f(h));
        }
        #pragma unroll
        for (int nf = 0; nf < 8; ++nf) {
            size_t off = (((size_t)kb * 8 + nf) * 64 + l) * 8;
            bf16x8 bhl = *(const bf16x8*)&hpl[off];
            bf16x8 bll = *(const bf16x8*)&lpl[off];
            bf16x8 bhr = *(const bf16x8*)&hpr[off];
            bf16x8 blr = *(const bf16x8*)&lpr[off];
            accl[nf] = __builtin_amdgcn_mfma_f32_16x16x32_bf16(ahi, bhl, accl[nf], 0, 0, 0);
            accl[nf] = __builtin_amdgcn_mfma_f32_16x16x32_bf16(ahi, bll, accl[nf], 0, 0, 0);
            accl[nf] = __builtin_amdgcn_mfma_f32_16x16x32_bf16(alo, bhl, accl[nf], 0, 0, 0);
            accr[nf] = __builtin_amdgcn_mfma_f32_16x16x32_bf16(ahi, bhr, accr[nf], 0, 0, 0);
            accr[nf] = __builtin_amdgcn_mfma_f32_16x16x32_bf16(ahi, blr, accr[nf], 0, 0, 0);
            accr[nf] = __builtin_amdgcn_mfma_f32_16x16x32_bf16(alo, bhr, accr[nf], 0, 0, 0);
        }
    }

    // C/D layout: col = nf*16 + m15, row = g*4 + r; store at interleaved pos
    #pragma unroll
    for (int nf = 0; nf < 8; ++nf) {
        int col = nf * 16 + m15;
        int newpos = ((nf & 3) * 4 + (m15 >> 2)) * 8 + (nf >> 2) * 4 + (m15 & 3);
        float vbl = bl[col];
        float vbr = br[col];
        #pragma unroll
        for (int r = 0; r < 4; ++r) {
            int row = rowbase + g * 4 + r;
            if (row < nrows) {
                xlh[(size_t)row * 128 + newpos] = (_Float16)(accl[nf][r] + vbl);
                xrh[(size_t)row * 128 + newpos] = (_Float16)(accr[nf][r] + vbr);
            }
        }
    }
}

// ---------------------------------------------------------------------------
// Fused GATv2 aggregation — 4 groups x 16 lanes, no-max softmax, DPP rowsum.
// Interleaved FP16 xl/xr: ONE 16B gather per edge. Depth-2 rotated prefetch
// (3 gathers in flight per group). Optional fused output projection.
// ---------------------------------------------------------------------------
__device__ __forceinline__ float dsel(float4 a, float4 x, float4 tp, float4 tn) {
    float r, v;
    v = a.x + x.x; r  = v * (v > 0.f ? tp.x : tn.x);
    v = a.y + x.y; r += v * (v > 0.f ? tp.y : tn.y);
    v = a.z + x.z; r += v * (v > 0.f ? tp.z : tn.z);
    v = a.w + x.w; r += v * (v > 0.f ? tp.w : tn.w);
    return r;
}

__global__ __launch_bounds__(256) void gat_aggregate(
        const _Float16* __restrict__ xlh, const _Float16* __restrict__ xrh,
        const int* __restrict__ rowptr, const int* __restrict__ esrc,
        const float* __restrict__ att, const float* __restrict__ bias,
        float* __restrict__ hout, int n, int do_relu,
        const float* __restrict__ Wout, const float* __restrict__ bout,
        float* __restrict__ out4) {
    int node = (int)((blockIdx.x * blockDim.x + threadIdx.x) >> 6);
    int lane = threadIdx.x & 63;
    if (node >= n) return;
    int g  = lane >> 4;
    int gl = lane & 15;
    int c0 = gl * 4;

    half8 xrh8 = *(const half8*)&xrh[(size_t)node * 128 + gl * 8];
    float4 xr0 = make_float4((float)xrh8[0], (float)xrh8[1],
                             (float)xrh8[2], (float)xrh8[3]);
    float4 xr1 = make_float4((float)xrh8[4], (float)xrh8[5],
                             (float)xrh8[6], (float)xrh8[7]);
    float4 atp0 = *(const float4*)&att[c0];
    float4 atp1 = *(const float4*)&att[64 + c0];
    float4 atn0 = make_float4(NEG * atp0.x, NEG * atp0.y, NEG * atp0.z, NEG * atp0.w);
    float4 atn1 = make_float4(NEG * atp1.x, NEG * atp1.y, NEG * atp1.z, NEG * atp1.w);

    float s0 = 0.f, s1 = 0.f;
    float4 acc0 = make_float4(0.f, 0.f, 0.f, 0.f);
    float4 acc1 = make_float4(0.f, 0.f, 0.f, 0.f);

    int pbeg = rowptr[node], pend = rowptr[node + 1];
    int p = pbeg + g;
    bool v0 = p < pend;
    bool v1 = p + 4 < pend;
    half8 r0 = (half8)(_Float16)0.f, r1 = r0;
    if (v0) r0 = *(const half8*)&xlh[(size_t)esrc[p] * 128 + gl * 8];
    if (v1) r1 = *(const half8*)&xlh[(size_t)esrc[p + 4] * 128 + gl * 8];

    while (v0) {
        bool v2 = p + 8 < pend;              // uniform within 16-lane group
        half8 r2 = (half8)(_Float16)0.f;
        if (v2) r2 = *(const half8*)&xlh[(size_t)esrc[p + 8] * 128 + gl * 8];

        float4 a0 = make_float4((float)r0[0], (float)r0[1],
                                (float)r0[2], (float)r0[3]);
        float4 a1 = make_float4((float)r0[4], (float)r0[5],
                                (float)r0[6], (float)r0[7]);
        float t0 = rowsum16(dsel(a0, xr0, atp0, atn0));
        float t1 = rowsum16(dsel(a1, xr1, atp1, atn1));
        float p0 = __expf(fminf(t0, 80.f));
        float p1 = __expf(fminf(t1, 80.f));
        s0 += p0;  s1 += p1;
        acc0.x += p0 * a0.x;  acc0.y += p0 * a0.y;
        acc0.z += p0 * a0.z;  acc0.w += p0 * a0.w;
        acc1.x += p1 * a1.x;  acc1.y += p1 * a1.y;
        acc1.z += p1 * a1.z;  acc1.w += p1 * a1.w;

        r0 = r1; r1 = r2; v0 = v1; v1 = v2; p += 4;
    }

    // butterfly sum across the 4 groups (xor 16 then 32)
    #pragma unroll
    for (int off = 16; off <= 32; off <<= 1) {
        s0 += __shfl_xor(s0, off, 64);
        s1 += __shfl_xor(s1, off, 64);
        acc0.x += __shfl_xor(acc0.x, off, 64); acc0.y += __shfl_xor(acc0.y, off, 64);
        acc0.z += __shfl_xor(acc0.z, off, 64); acc0.w += __shfl_xor(acc0.w, off, 64);
        acc1.x += __shfl_xor(acc1.x, off, 64); acc1.y += __shfl_xor(acc1.y, off, 64);
        acc1.z += __shfl_xor(acc1.z, off, 64); acc1.w += __shfl_xor(acc1.w, off, 64);
    }

    float inv0 = 1.f / s0, inv1 = 1.f / s1;

    if (out4) {
        float o0[4], o1[4];
        float a0v[4] = {acc0.x, acc0.y, acc0.z, acc0.w};
        float a1v[4] = {acc1.x, acc1.y, acc1.z, acc1.w};
        #pragma unroll
        for (int i = 0; i < 4; ++i) {
            o0[i] = a0v[i] * inv0 + bias[c0 + i];
            o1[i] = a1v[i] * inv1 + bias[64 + c0 + i];
            if (do_relu) { o0[i] = fmaxf(o0[i], 0.f); o1[i] = fmaxf(o1[i], 0.f); }
        }
        float p0 = 0.f, p1 = 0.f, p2 = 0.f, p3 = 0.f;
        #pragma unroll
        for (int i = 0; i < 4; ++i) {
            float4 w = *(const float4*)&Wout[(c0 + i) * 4];
            p0 += o0[i] * w.x; p1 += o0[i] * w.y; p2 += o0[i] * w.z; p3 += o0[i] * w.w;
        }
        #pragma unroll
        for (int i = 0; i < 4; ++i) {
            float4 w = *(const float4*)&Wout[(64 + c0 + i) * 4];
            p0 += o1[i] * w.x; p1 += o1[i] * w.y; p2 += o1[i] * w.z; p3 += o1[i] * w.w;
        }
        p0 = rowsum16(p0); p1 = rowsum16(p1);
        p2 = rowsum16(p2); p3 = rowsum16(p3);
        if (lane == 0) {
            float4 o = make_float4(p0 + bout[0], p1 + bout[1],
                                   p2 + bout[2], p3 + bout[3]);
            *(float4*)&out4[(size_t)node * 4] = o;
        }
        return;
    }

    if (g == 0) {
        float4 vb = *(const float4*)&bias[c0];
        float4 o = make_float4(acc0.x * inv0 + vb.x, acc0.y * inv0 + vb.y,
                               acc0.z * inv0 + vb.z, acc0.w * inv0 + vb.w);
        if (do_relu) {
            o.x = fmaxf(o.x, 0.f); o.y = fmaxf(o.y, 0.f);
            o.z = fmaxf(o.z, 0.f); o.w = fmaxf(o.w, 0.f);
        }
        *(float4*)&hout[(size_t)node * 128 + c0] = o;
    } else if (g == 1) {
        float4 vb = *(const float4*)&bias[64 + c0];
        float4 o = make_float4(acc1.x * inv1 + vb.x, acc1.y * inv1 + vb.y,
                               acc1.z * inv1 + vb.z, acc1.w * inv1 + vb.w);
        if (do_relu) {
            o.x = fmaxf(o.x, 0.f); o.y = fmaxf(o.y, 0.f);
            o.z = fmaxf(o.z, 0.f); o.w = fmaxf(o.w, 0.f);
        }
        *(float4*)&hout[(size_t)node * 128 + 64 + c0] = o;
    }
}

// ---------------------------------------------------------------------------
extern "C" void kernel_launch(void* const* d_in, const int* in_sizes, int n_in,
                              void* d_out, int out_size, void* d_ws,
                              size_t ws_size, hipStream_t stream) {
    // setup_inputs order:
    //  0:x 1:edge_index 2:W1l 3:b1l 4:W1r 5:b1r 6:att1 7:bias1
    //  8:W2l 9:b2l 10:W2r 11:b2r 12:att2 13:bias2
    // 14:W3l 15:b3l 16:W3r 17:b3r 18:att3 19:bias3 20:Wout 21:bout
    const float* x    = (const float*)d_in[0];
    const int*   ei   = (const int*)  d_in[1];
    const float* W1l  = (const float*)d_in[2];
    const float* b1l  = (const float*)d_in[3];
    const float* W1r  = (const float*)d_in[4];
    const float* b1r  = (const float*)d_in[5];
    const float* att1 = (const float*)d_in[6];
    const float* bias1= (const float*)d_in[7];
    const float* W2l  = (const float*)d_in[8];
    const float* b2l  = (const float*)d_in[9];
    const float* W2r  = (const float*)d_in[10];
    const float* b2r  = (const float*)d_in[11];
    const float* att2 = (const float*)d_in[12];
    const float* bias2= (const float*)d_in[13];
    const float* W3l  = (const float*)d_in[14];
    const float* b3l  = (const float*)d_in[15];
    const float* W3r  = (const float*)d_in[16];
    const float* b3r  = (const float*)d_in[17];
    const float* att3 = (const float*)d_in[18];
    const float* bias3= (const float*)d_in[19];
    const float* Wout = (const float*)d_in[20];
    const float* bout = (const float*)d_in[21];

    int N    = in_sizes[0] / DIN;
    int E    = in_sizes[1] / 2;
    int Etot = E + N;

    char* base = (char*)d_ws;
    float* h = (float*)base;              base += (size_t)N * HC * 4;
    _Float16* xlh = (_Float16*)base;      base += (size_t)N * HC * 2;
    _Float16* xrh = (_Float16*)base;      base += (size_t)N * HC * 2;
    unsigned short* whi = (unsigned short*)base;  base += 6 * 16384 * 2;
    unsigned short* wlo = (unsigned short*)base;  base += 6 * 16384 * 2;
    int* esrc   = (int*)base;             base += (size_t)Etot * 4;
    int* rowptr = (int*)base;             base += (size_t)(((N + 1) + 3) & ~3) * 4;
    int* cursor = (int*)base;             base += (size_t)N * 4;
    int* counts = (int*)base;

    hipMemsetAsync(counts, 0, (size_t)N * sizeof(int), stream);
    hist_kernel<<<(Etot + 255) / 256, 256, 0, stream>>>(ei, E, N, counts);
    scan_kernel<<<1, 1024, 0, stream>>>(counts, rowptr, cursor, N);
    scatter_kernel<<<(Etot + 255) / 256, 256, 0, stream>>>(ei, E, N, cursor, esrc);
    prep_w<<<dim3(8, 6), 256, 0, stream>>>(W1l, W1r, W2l, W2r, W3l, W3r, whi, wlo);

    int gemm_grid = (N + 63) / 64;
    int agg_grid  = (N + 3) / 4;

    gemm_mfma_dual<<<gemm_grid, 256, 0, stream>>>(x, whi, wlo, 0, b1l, b1r, xlh, xrh, N);
    gat_aggregate<<<agg_grid, 256, 0, stream>>>(xlh, xrh, rowptr, esrc, att1, bias1,
                                                h, N, 1, nullptr, nullptr, nullptr);
    gemm_mfma_dual<<<gemm_grid, 256, 0, stream>>>(h, whi, wlo, 2, b2l, b2r, xlh, xrh, N);
    gat_aggregate<<<agg_grid, 256, 0, stream>>>(xlh, xrh, rowptr, esrc, att2, bias2,
                                                h, N, 1, nullptr, nullptr, nullptr);
    gemm_mfma_dual<<<gemm_grid, 256, 0, stream>>>(h, whi, wlo, 4, b3l, b3r, xlh, xrh, N);
    // layer 3: fused relu + output projection, h never materialized
    gat_aggregate<<<agg_grid, 256, 0, stream>>>(xlh, xrh, rowptr, esrc, att3, bias3,
                                                nullptr, N, 1, Wout, bout,
                                                (float*)d_out);
}

// Round 12
// 373.081 us; speedup vs baseline: 1.0515x; 1.0515x over previous
//
#include <hip/hip_runtime.h>
#include <math.h>

#define DIN  128
#define HC   128
#define NEG  0.2f

typedef __attribute__((ext_vector_type(8))) short bf16x8;
typedef __attribute__((ext_vector_type(4))) float f32x4;
typedef __attribute__((ext_vector_type(8))) _Float16 half8;

__device__ __forceinline__ unsigned short f2bf_rne(float x) {
    unsigned u = __float_as_uint(x);
    unsigned r = u + 0x7FFFu + ((u >> 16) & 1u);
    return (unsigned short)(r >> 16);
}
__device__ __forceinline__ float bf2f(unsigned short h) {
    return __uint_as_float(((unsigned)h) << 16);
}

// 16-lane (DPP-row) butterfly sum: xor1, xor2, xor7, xor15 — pure VALU.
template <int CTRL>
__device__ __forceinline__ float dpp_xadd(float x) {
    int r = __builtin_amdgcn_update_dpp(0, __float_as_int(x), CTRL, 0xF, 0xF, true);
    return x + __int_as_float(r);
}
__device__ __forceinline__ float rowsum16(float x) {
    x = dpp_xadd<0xB1>(x);   // lane ^ 1
    x = dpp_xadd<0x4E>(x);   // lane ^ 2
    x = dpp_xadd<0x141>(x);  // lane ^ 7
    x = dpp_xadd<0x140>(x);  // lane ^ 15
    return x;
}

// ---------------------------------------------------------------------------
// CSR build
// ---------------------------------------------------------------------------
__global__ void hist_kernel(const int* __restrict__ ei, int E, int N,
                            int* __restrict__ counts) {
    int i = blockIdx.x * blockDim.x + threadIdx.x;
    int Etot = E + N;
    if (i >= Etot) return;
    int dst = (i < E) ? ei[E + i] : (i - E);
    if (dst < 0 || dst >= N) return;
    atomicAdd(&counts[dst], 1);
}

__global__ void scan_kernel(const int* __restrict__ counts,
                            int* __restrict__ rowptr,
                            int* __restrict__ cursor, int n) {
    __shared__ int wsum[16];
    int tid  = threadIdx.x;          // 1024 threads
    int lane = tid & 63, wid = tid >> 6;
    int running = 0;
    for (int base = 0; base < n; base += 4096) {
        int i = base + tid * 4;
        int4 v = make_int4(0, 0, 0, 0);
        if (i < n) v = *(const int4*)&counts[i];   // n % 4 == 0
        int ssum = v.x + v.y + v.z + v.w;
        int x = ssum;
        #pragma unroll
        for (int off = 1; off < 64; off <<= 1) {
            int y = __shfl_up(x, off, 64);
            if (lane >= off) x += y;
        }
        if (lane == 63) wsum[wid] = x;
        __syncthreads();
        if (tid < 16) {
            int w = wsum[tid];
            #pragma unroll
            for (int off = 1; off < 16; off <<= 1) {
                int y = __shfl_up(w, off, 64);
                if (tid >= off) w += y;
            }
            wsum[tid] = w;
        }
        __syncthreads();
        int excl = running + (wid ? wsum[wid - 1] : 0) + (x - ssum);
        if (i < n) {
            int4 r;
            r.x = excl;
            r.y = r.x + v.x;
            r.z = r.y + v.y;
            r.w = r.z + v.z;
            *(int4*)&rowptr[i] = r;
            *(int4*)&cursor[i] = r;
        }
        running += wsum[15];
        __syncthreads();
    }
    if (tid == 0) rowptr[n] = running;
}

__global__ void scatter_kernel(const int* __restrict__ ei, int E, int N,
                               int* __restrict__ cursor,
                               int* __restrict__ esrc) {
    int i = blockIdx.x * blockDim.x + threadIdx.x;
    int Etot = E + N;
    if (i >= Etot) return;
    int src = (i < E) ? ei[i]     : (i - E);
    int dst = (i < E) ? ei[E + i] : (i - E);
    if (dst < 0 || dst >= N || src < 0 || src >= N) return;
    int pos = atomicAdd(&cursor[dst], 1);
    esrc[pos] = src;
}

// ---------------------------------------------------------------------------
// W prep: split each 128x128 W into bf16 hi/lo, packed in MFMA B-fragment
// order: slot (kb,nf,lane,j) = W[kb*32 + (lane>>4)*8 + j][nf*16 + (lane&15)].
// ---------------------------------------------------------------------------
__global__ __launch_bounds__(256) void prep_w(
        const float* __restrict__ W1l, const float* __restrict__ W1r,
        const float* __restrict__ W2l, const float* __restrict__ W2r,
        const float* __restrict__ W3l, const float* __restrict__ W3r,
        unsigned short* __restrict__ hi, unsigned short* __restrict__ lo) {
    int m = blockIdx.y;
    const float* W = (m == 0) ? W1l : (m == 1) ? W1r : (m == 2) ? W2l
                   : (m == 3) ? W2r : (m == 4) ? W3l : W3r;
    int t = blockIdx.x * 256 + threadIdx.x;    // 0..2047 (grid.x = 8)
    int kb = t >> 9, nf = (t >> 6) & 7, l = t & 63;
    int col = nf * 16 + (l & 15);
    int k0  = kb * 32 + (l >> 4) * 8;
    size_t ob = ((size_t)m * 2048 + t) * 8;
    #pragma unroll
    for (int j = 0; j < 8; ++j) {
        float v = W[(size_t)(k0 + j) * 128 + col];
        unsigned short h = f2bf_rne(v);
        hi[ob + j] = h;
        lo[ob + j] = f2bf_rne(v - bf2f(h));
    }
}

// ---------------------------------------------------------------------------
// Dual MFMA GEMM (split-bf16, 3 terms). Outputs stored FP16 in the
// INTERLEAVED per-lane layout consumed by gat_aggregate:
//   newpos(col) = (4*(nf&3) + (m15>>2))*8 + (nf>>2)*4 + (m15&3)
// The permutation is applied in LDS (16 KB tile), then copied to global as
// contiguous half8 — fully coalesced 16B stores (round-11's direct scattered
// 2B stores cost ~+45 us across the 3 dispatches).
// ---------------------------------------------------------------------------
__global__ __launch_bounds__(256) void gemm_mfma_dual(
        const float* __restrict__ X,
        const unsigned short* __restrict__ Whi,
        const unsigned short* __restrict__ Wlo, int matbase,
        const float* __restrict__ bl, const float* __restrict__ br,
        _Float16* __restrict__ xlh, _Float16* __restrict__ xrh, int nrows) {
    const unsigned short* hpl = Whi + ((size_t)(matbase + 0) * 16384);
    const unsigned short* lpl = Wlo + ((size_t)(matbase + 0) * 16384);
    const unsigned short* hpr = Whi + ((size_t)(matbase + 1) * 16384);
    const unsigned short* lpr = Wlo + ((size_t)(matbase + 1) * 16384);

    __shared__ _Float16 st[64][128];     // 16 KB staging tile

    int tid = threadIdx.x;
    int w   = tid >> 6;
    int l   = tid & 63;
    int m15 = l & 15, g = l >> 4;
    int rowbase = blockIdx.x * 64 + w * 16;

    f32x4 accl[8], accr[8];
    #pragma unroll
    for (int nf = 0; nf < 8; ++nf) {
        accl[nf] = (f32x4){0.f, 0.f, 0.f, 0.f};
        accr[nf] = (f32x4){0.f, 0.f, 0.f, 0.f};
    }

    #pragma unroll
    for (int kb = 0; kb < 4; ++kb) {
        int arow = rowbase + m15;
        float4 x0 = make_float4(0.f, 0.f, 0.f, 0.f), x1 = x0;
        if (arow < nrows) {
            const float* xp = &X[(size_t)arow * 128 + kb * 32 + g * 8];
            x0 = *(const float4*)xp;
            x1 = *(const float4*)(xp + 4);
        }
        float xv[8] = {x0.x, x0.y, x0.z, x0.w, x1.x, x1.y, x1.z, x1.w};
        bf16x8 ahi, alo;
        #pragma unroll
        for (int j = 0; j < 8; ++j) {
            unsigned short h = f2bf_rne(xv[j]);
            ahi[j] = (short)h;
            alo[j] = (short)f2bf_rne(xv[j] - bf2f(h));
        }
        #pragma unroll
        for (int nf = 0; nf < 8; ++nf) {
            size_t off = (((size_t)kb * 8 + nf) * 64 + l) * 8;
            bf16x8 bhl = *(const bf16x8*)&hpl[off];
            bf16x8 bll = *(const bf16x8*)&lpl[off];
            bf16x8 bhr = *(const bf16x8*)&hpr[off];
            bf16x8 blr = *(const bf16x8*)&lpr[off];
            accl[nf] = __builtin_amdgcn_mfma_f32_16x16x32_bf16(ahi, bhl, accl[nf], 0, 0, 0);
            accl[nf] = __builtin_amdgcn_mfma_f32_16x16x32_bf16(ahi, bll, accl[nf], 0, 0, 0);
            accl[nf] = __builtin_amdgcn_mfma_f32_16x16x32_bf16(alo, bhl, accl[nf], 0, 0, 0);
            accr[nf] = __builtin_amdgcn_mfma_f32_16x16x32_bf16(ahi, bhr, accr[nf], 0, 0, 0);
            accr[nf] = __builtin_amdgcn_mfma_f32_16x16x32_bf16(ahi, blr, accr[nf], 0, 0, 0);
            accr[nf] = __builtin_amdgcn_mfma_f32_16x16x32_bf16(alo, bhr, accr[nf], 0, 0, 0);
        }
    }

    int blk0 = blockIdx.x * 64;

    // ---- xl: scatter into LDS, coalesced copy out ----
    #pragma unroll
    for (int nf = 0; nf < 8; ++nf) {
        int col = nf * 16 + m15;
        int newpos = ((nf & 3) * 4 + (m15 >> 2)) * 8 + (nf >> 2) * 4 + (m15 & 3);
        float vbl = bl[col];
        #pragma unroll
        for (int r = 0; r < 4; ++r)
            st[w * 16 + g * 4 + r][newpos] = (_Float16)(accl[nf][r] + vbl);
    }
    __syncthreads();
    #pragma unroll
    for (int it = 0; it < 4; ++it) {
        int f   = it * 256 + tid;            // half8 index in 64x128 tile
        int row = f >> 4, c8 = f & 15;
        if (blk0 + row < nrows)
            *(half8*)&xlh[(size_t)(blk0 + row) * 128 + c8 * 8] =
                *(const half8*)&st[row][c8 * 8];
    }
    __syncthreads();

    // ---- xr: scatter into LDS, coalesced copy out ----
    #pragma unroll
    for (int nf = 0; nf < 8; ++nf) {
        int col = nf * 16 + m15;
        int newpos = ((nf & 3) * 4 + (m15 >> 2)) * 8 + (nf >> 2) * 4 + (m15 & 3);
        float vbr = br[col];
        #pragma unroll
        for (int r = 0; r < 4; ++r)
            st[w * 16 + g * 4 + r][newpos] = (_Float16)(accr[nf][r] + vbr);
    }
    __syncthreads();
    #pragma unroll
    for (int it = 0; it < 4; ++it) {
        int f   = it * 256 + tid;
        int row = f >> 4, c8 = f & 15;
        if (blk0 + row < nrows)
            *(half8*)&xrh[(size_t)(blk0 + row) * 128 + c8 * 8] =
                *(const half8*)&st[row][c8 * 8];
    }
}

// ---------------------------------------------------------------------------
// Fused GATv2 aggregation — 4 groups x 16 lanes, no-max softmax, DPP rowsum.
// Interleaved FP16 xl/xr: ONE 16B gather per edge. Depth-2 rotated prefetch
// (3 gathers in flight per group). Optional fused output projection.
// ---------------------------------------------------------------------------
__device__ __forceinline__ float dsel(float4 a, float4 x, float4 tp, float4 tn) {
    float r, v;
    v = a.x + x.x; r  = v * (v > 0.f ? tp.x : tn.x);
    v = a.y + x.y; r += v * (v > 0.f ? tp.y : tn.y);
    v = a.z + x.z; r += v * (v > 0.f ? tp.z : tn.z);
    v = a.w + x.w; r += v * (v > 0.f ? tp.w : tn.w);
    return r;
}

__global__ __launch_bounds__(256) void gat_aggregate(
        const _Float16* __restrict__ xlh, const _Float16* __restrict__ xrh,
        const int* __restrict__ rowptr, const int* __restrict__ esrc,
        const float* __restrict__ att, const float* __restrict__ bias,
        float* __restrict__ hout, int n, int do_relu,
        const float* __restrict__ Wout, const float* __restrict__ bout,
        float* __restrict__ out4) {
    int node = (int)((blockIdx.x * blockDim.x + threadIdx.x) >> 6);
    int lane = threadIdx.x & 63;
    if (node >= n) return;
    int g  = lane >> 4;
    int gl = lane & 15;
    int c0 = gl * 4;

    half8 xrh8 = *(const half8*)&xrh[(size_t)node * 128 + gl * 8];
    float4 xr0 = make_float4((float)xrh8[0], (float)xrh8[1],
                             (float)xrh8[2], (float)xrh8[3]);
    float4 xr1 = make_float4((float)xrh8[4], (float)xrh8[5],
                             (float)xrh8[6], (float)xrh8[7]);
    float4 atp0 = *(const float4*)&att[c0];
    float4 atp1 = *(const float4*)&att[64 + c0];
    float4 atn0 = make_float4(NEG * atp0.x, NEG * atp0.y, NEG * atp0.z, NEG * atp0.w);
    float4 atn1 = make_float4(NEG * atp1.x, NEG * atp1.y, NEG * atp1.z, NEG * atp1.w);

    float s0 = 0.f, s1 = 0.f;
    float4 acc0 = make_float4(0.f, 0.f, 0.f, 0.f);
    float4 acc1 = make_float4(0.f, 0.f, 0.f, 0.f);

    int pbeg = rowptr[node], pend = rowptr[node + 1];
    int p = pbeg + g;
    bool v0 = p < pend;
    bool v1 = p + 4 < pend;
    half8 r0 = (half8)(_Float16)0.f, r1 = r0;
    if (v0) r0 = *(const half8*)&xlh[(size_t)esrc[p] * 128 + gl * 8];
    if (v1) r1 = *(const half8*)&xlh[(size_t)esrc[p + 4] * 128 + gl * 8];

    while (v0) {
        bool v2 = p + 8 < pend;              // uniform within 16-lane group
        half8 r2 = (half8)(_Float16)0.f;
        if (v2) r2 = *(const half8*)&xlh[(size_t)esrc[p + 8] * 128 + gl * 8];

        float4 a0 = make_float4((float)r0[0], (float)r0[1],
                                (float)r0[2], (float)r0[3]);
        float4 a1 = make_float4((float)r0[4], (float)r0[5],
                                (float)r0[6], (float)r0[7]);
        float t0 = rowsum16(dsel(a0, xr0, atp0, atn0));
        float t1 = rowsum16(dsel(a1, xr1, atp1, atn1));
        float p0 = __expf(fminf(t0, 80.f));
        float p1 = __expf(fminf(t1, 80.f));
        s0 += p0;  s1 += p1;
        acc0.x += p0 * a0.x;  acc0.y += p0 * a0.y;
        acc0.z += p0 * a0.z;  acc0.w += p0 * a0.w;
        acc1.x += p1 * a1.x;  acc1.y += p1 * a1.y;
        acc1.z += p1 * a1.z;  acc1.w += p1 * a1.w;

        r0 = r1; r1 = r2; v0 = v1; v1 = v2; p += 4;
    }

    // butterfly sum across the 4 groups (xor 16 then 32)
    #pragma unroll
    for (int off = 16; off <= 32; off <<= 1) {
        s0 += __shfl_xor(s0, off, 64);
        s1 += __shfl_xor(s1, off, 64);
        acc0.x += __shfl_xor(acc0.x, off, 64); acc0.y += __shfl_xor(acc0.y, off, 64);
        acc0.z += __shfl_xor(acc0.z, off, 64); acc0.w += __shfl_xor(acc0.w, off, 64);
        acc1.x += __shfl_xor(acc1.x, off, 64); acc1.y += __shfl_xor(acc1.y, off, 64);
        acc1.z += __shfl_xor(acc1.z, off, 64); acc1.w += __shfl_xor(acc1.w, off, 64);
    }

    float inv0 = 1.f / s0, inv1 = 1.f / s1;

    if (out4) {
        float o0[4], o1[4];
        float a0v[4] = {acc0.x, acc0.y, acc0.z, acc0.w};
        float a1v[4] = {acc1.x, acc1.y, acc1.z, acc1.w};
        #pragma unroll
        for (int i = 0; i < 4; ++i) {
            o0[i] = a0v[i] * inv0 + bias[c0 + i];
            o1[i] = a1v[i] * inv1 + bias[64 + c0 + i];
            if (do_relu) { o0[i] = fmaxf(o0[i], 0.f); o1[i] = fmaxf(o1[i], 0.f); }
        }
        float p0 = 0.f, p1 = 0.f, p2 = 0.f, p3 = 0.f;
        #pragma unroll
        for (int i = 0; i < 4; ++i) {
            float4 w = *(const float4*)&Wout[(c0 + i) * 4];
            p0 += o0[i] * w.x; p1 += o0[i] * w.y; p2 += o0[i] * w.z; p3 += o0[i] * w.w;
        }
        #pragma unroll
        for (int i = 0; i < 4; ++i) {
            float4 w = *(const float4*)&Wout[(64 + c0 + i) * 4];
            p0 += o1[i] * w.x; p1 += o1[i] * w.y; p2 += o1[i] * w.z; p3 += o1[i] * w.w;
        }
        p0 = rowsum16(p0); p1 = rowsum16(p1);
        p2 = rowsum16(p2); p3 = rowsum16(p3);
        if (lane == 0) {
            float4 o = make_float4(p0 + bout[0], p1 + bout[1],
                                   p2 + bout[2], p3 + bout[3]);
            *(float4*)&out4[(size_t)node * 4] = o;
        }
        return;
    }

    if (g == 0) {
        float4 vb = *(const float4*)&bias[c0];
        float4 o = make_float4(acc0.x * inv0 + vb.x, acc0.y * inv0 + vb.y,
                               acc0.z * inv0 + vb.z, acc0.w * inv0 + vb.w);
        if (do_relu) {
            o.x = fmaxf(o.x, 0.f); o.y = fmaxf(o.y, 0.f);
            o.z = fmaxf(o.z, 0.f); o.w = fmaxf(o.w, 0.f);
        }
        *(float4*)&hout[(size_t)node * 128 + c0] = o;
    } else if (g == 1) {
        float4 vb = *(const float4*)&bias[64 + c0];
        float4 o = make_float4(acc1.x * inv1 + vb.x, acc1.y * inv1 + vb.y,
                               acc1.z * inv1 + vb.z, acc1.w * inv1 + vb.w);
        if (do_relu) {
            o.x = fmaxf(o.x, 0.f); o.y = fmaxf(o.y, 0.f);
            o.z = fmaxf(o.z, 0.f); o.w = fmaxf(o.w, 0.f);
        }
        *(float4*)&hout[(size_t)node * 128 + 64 + c0] = o;
    }
}

// ---------------------------------------------------------------------------
extern "C" void kernel_launch(void* const* d_in, const int* in_sizes, int n_in,
                              void* d_out, int out_size, void* d_ws,
                              size_t ws_size, hipStream_t stream) {
    // setup_inputs order:
    //  0:x 1:edge_index 2:W1l 3:b1l 4:W1r 5:b1r 6:att1 7:bias1
    //  8:W2l 9:b2l 10:W2r 11:b2r 12:att2 13:bias2
    // 14:W3l 15:b3l 16:W3r 17:b3r 18:att3 19:bias3 20:Wout 21:bout
    const float* x    = (const float*)d_in[0];
    const int*   ei   = (const int*)  d_in[1];
    const float* W1l  = (const float*)d_in[2];
    const float* b1l  = (const float*)d_in[3];
    const float* W1r  = (const float*)d_in[4];
    const float* b1r  = (const float*)d_in[5];
    const float* att1 = (const float*)d_in[6];
    const float* bias1= (const float*)d_in[7];
    const float* W2l  = (const float*)d_in[8];
    const float* b2l  = (const float*)d_in[9];
    const float* W2r  = (const float*)d_in[10];
    const float* b2r  = (const float*)d_in[11];
    const float* att2 = (const float*)d_in[12];
    const float* bias2= (const float*)d_in[13];
    const float* W3l  = (const float*)d_in[14];
    const float* b3l  = (const float*)d_in[15];
    const float* W3r  = (const float*)d_in[16];
    const float* b3r  = (const float*)d_in[17];
    const float* att3 = (const float*)d_in[18];
    const float* bias3= (const float*)d_in[19];
    const float* Wout = (const float*)d_in[20];
    const float* bout = (const float*)d_in[21];

    int N    = in_sizes[0] / DIN;
    int E    = in_sizes[1] / 2;
    int Etot = E + N;

    char* base = (char*)d_ws;
    float* h = (float*)base;              base += (size_t)N * HC * 4;
    _Float16* xlh = (_Float16*)base;      base += (size_t)N * HC * 2;
    _Float16* xrh = (_Float16*)base;      base += (size_t)N * HC * 2;
    unsigned short* whi = (unsigned short*)base;  base += 6 * 16384 * 2;
    unsigned short* wlo = (unsigned short*)base;  base += 6 * 16384 * 2;
    int* esrc   = (int*)base;             base += (size_t)Etot * 4;
    int* rowptr = (int*)base;             base += (size_t)(((N + 1) + 3) & ~3) * 4;
    int* cursor = (int*)base;             base += (size_t)N * 4;
    int* counts = (int*)base;

    hipMemsetAsync(counts, 0, (size_t)N * sizeof(int), stream);
    hist_kernel<<<(Etot + 255) / 256, 256, 0, stream>>>(ei, E, N, counts);
    scan_kernel<<<1, 1024, 0, stream>>>(counts, rowptr, cursor, N);
    scatter_kernel<<<(Etot + 255) / 256, 256, 0, stream>>>(ei, E, N, cursor, esrc);
    prep_w<<<dim3(8, 6), 256, 0, stream>>>(W1l, W1r, W2l, W2r, W3l, W3r, whi, wlo);

    int gemm_grid = (N + 63) / 64;
    int agg_grid  = (N + 3) / 4;

    gemm_mfma_dual<<<gemm_grid, 256, 0, stream>>>(x, whi, wlo, 0, b1l, b1r, xlh, xrh, N);
    gat_aggregate<<<agg_grid, 256, 0, stream>>>(xlh, xrh, rowptr, esrc, att1, bias1,
                                                h, N, 1, nullptr, nullptr, nullptr);
    gemm_mfma_dual<<<gemm_grid, 256, 0, stream>>>(h, whi, wlo, 2, b2l, b2r, xlh, xrh, N);
    gat_aggregate<<<agg_grid, 256, 0, stream>>>(xlh, xrh, rowptr, esrc, att2, bias2,
                                                h, N, 1, nullptr, nullptr, nullptr);
    gemm_mfma_dual<<<gemm_grid, 256, 0, stream>>>(h, whi, wlo, 4, b3l, b3r, xlh, xrh, N);
    // layer 3: fused relu + output projection, h never materialized
    gat_aggregate<<<agg_grid, 256, 0, stream>>>(xlh, xrh, rowptr, esrc, att3, bias3,
                                                nullptr, N, 1, Wout, bout,
                                                (float*)d_out);
}

// Round 13
// 361.458 us; speedup vs baseline: 1.0853x; 1.0322x over previous
//
#include <hip/hip_runtime.h>
#include <math.h>

#define DIN  128
#define HC   128
#define NEG  0.2f

typedef __attribute__((ext_vector_type(8))) short bf16x8;
typedef __attribute__((ext_vector_type(4))) float f32x4;
typedef __attribute__((ext_vector_type(8))) _Float16 half8;
typedef __attribute__((ext_vector_type(2))) _Float16 half2v;

__device__ __forceinline__ unsigned short f2bf_rne(float x) {
    unsigned u = __float_as_uint(x);
    unsigned r = u + 0x7FFFu + ((u >> 16) & 1u);
    return (unsigned short)(r >> 16);
}
__device__ __forceinline__ float bf2f(unsigned short h) {
    return __uint_as_float(((unsigned)h) << 16);
}

// stored position p (0..127)  ->  original channel column
__device__ __forceinline__ int colOf(int p) {
    return ((p >> 5) * 2 + (p & 1)) * 16 + ((p & 31) >> 1);
}

// DPP butterfly adds (pure VALU)
template <int CTRL>
__device__ __forceinline__ float dpp_xadd(float x) {
    int r = __builtin_amdgcn_update_dpp(0, __float_as_int(x), CTRL, 0xF, 0xF, true);
    return x + __int_as_float(r);
}
__device__ __forceinline__ float rowsum8(float x) {   // sum within 8-lane half-row
    x = dpp_xadd<0xB1>(x);   // lane ^ 1
    x = dpp_xadd<0x4E>(x);   // lane ^ 2
    x = dpp_xadd<0x141>(x);  // half-row mirror (lane ^ 7 within 8)
    return x;
}
__device__ __forceinline__ float rowsum16(float x) {
    x = dpp_xadd<0xB1>(x);
    x = dpp_xadd<0x4E>(x);
    x = dpp_xadd<0x141>(x);
    x = dpp_xadd<0x140>(x);  // row mirror (lane ^ 15)
    return x;
}

// ---------------------------------------------------------------------------
// CSR build
// ---------------------------------------------------------------------------
__global__ void hist_kernel(const int* __restrict__ ei, int E, int N,
                            int* __restrict__ counts) {
    int i = blockIdx.x * blockDim.x + threadIdx.x;
    int Etot = E + N;
    if (i >= Etot) return;
    int dst = (i < E) ? ei[E + i] : (i - E);
    if (dst < 0 || dst >= N) return;
    atomicAdd(&counts[dst], 1);
}

__global__ void scan_kernel(const int* __restrict__ counts,
                            int* __restrict__ rowptr,
                            int* __restrict__ cursor, int n) {
    __shared__ int wsum[16];
    int tid  = threadIdx.x;          // 1024 threads
    int lane = tid & 63, wid = tid >> 6;
    int running = 0;
    for (int base = 0; base < n; base += 4096) {
        int i = base + tid * 4;
        int4 v = make_int4(0, 0, 0, 0);
        if (i < n) v = *(const int4*)&counts[i];   // n % 4 == 0
        int ssum = v.x + v.y + v.z + v.w;
        int x = ssum;
        #pragma unroll
        for (int off = 1; off < 64; off <<= 1) {
            int y = __shfl_up(x, off, 64);
            if (lane >= off) x += y;
        }
        if (lane == 63) wsum[wid] = x;
        __syncthreads();
        if (tid < 16) {
            int w = wsum[tid];
            #pragma unroll
            for (int off = 1; off < 16; off <<= 1) {
                int y = __shfl_up(w, off, 64);
                if (tid >= off) w += y;
            }
            wsum[tid] = w;
        }
        __syncthreads();
        int excl = running + (wid ? wsum[wid - 1] : 0) + (x - ssum);
        if (i < n) {
            int4 r;
            r.x = excl;
            r.y = r.x + v.x;
            r.z = r.y + v.y;
            r.w = r.z + v.z;
            *(int4*)&rowptr[i] = r;
            *(int4*)&cursor[i] = r;
        }
        running += wsum[15];
        __syncthreads();
    }
    if (tid == 0) rowptr[n] = running;
}

__global__ void scatter_kernel(const int* __restrict__ ei, int E, int N,
                               int* __restrict__ cursor,
                               int* __restrict__ esrc) {
    int i = blockIdx.x * blockDim.x + threadIdx.x;
    int Etot = E + N;
    if (i >= Etot) return;
    int src = (i < E) ? ei[i]     : (i - E);
    int dst = (i < E) ? ei[E + i] : (i - E);
    if (dst < 0 || dst >= N || src < 0 || src >= N) return;
    int pos = atomicAdd(&cursor[dst], 1);
    esrc[pos] = src;
}

// ---------------------------------------------------------------------------
// W prep: split each 128x128 W into bf16 hi/lo, packed in MFMA B-fragment
// order. For layers 2/3 (m>=2) the k index refers to the PERMUTED h layout,
// so the W row is colOf(k).
// ---------------------------------------------------------------------------
__global__ __launch_bounds__(256) void prep_w(
        const float* __restrict__ W1l, const float* __restrict__ W1r,
        const float* __restrict__ W2l, const float* __restrict__ W2r,
        const float* __restrict__ W3l, const float* __restrict__ W3r,
        unsigned short* __restrict__ hi, unsigned short* __restrict__ lo) {
    int m = blockIdx.y;
    const float* W = (m == 0) ? W1l : (m == 1) ? W1r : (m == 2) ? W2l
                   : (m == 3) ? W2r : (m == 4) ? W3l : W3r;
    int t = blockIdx.x * 256 + threadIdx.x;    // 0..2047 (grid.x = 8)
    int kb = t >> 9, nf = (t >> 6) & 7, l = t & 63;
    int col = nf * 16 + (l & 15);
    int k0  = kb * 32 + (l >> 4) * 8;
    size_t ob = ((size_t)m * 2048 + t) * 8;
    #pragma unroll
    for (int j = 0; j < 8; ++j) {
        int k = k0 + j;
        int krow = (m >= 2) ? colOf(k) : k;
        float v = W[(size_t)krow * 128 + col];
        unsigned short h = f2bf_rne(v);
        hi[ob + j] = h;
        lo[ob + j] = f2bf_rne(v - bf2f(h));
    }
}

// ---------------------------------------------------------------------------
// Dual MFMA GEMM (split-bf16, 3 terms). Outputs stored FP16 at permuted
// position newpos(col) = (nf>>1)*32 + m15*2 + (nf&1): the (2a,2a+1) fragment
// pair packs into ONE 4B half2 store; 16 lanes -> 64B contiguous. No LDS.
// ---------------------------------------------------------------------------
__global__ __launch_bounds__(256) void gemm_mfma_dual(
        const float* __restrict__ X,
        const unsigned short* __restrict__ Whi,
        const unsigned short* __restrict__ Wlo, int matbase,
        const float* __restrict__ bl, const float* __restrict__ br,
        _Float16* __restrict__ xlh, _Float16* __restrict__ xrh, int nrows) {
    const unsigned short* hpl = Whi + ((size_t)(matbase + 0) * 16384);
    const unsigned short* lpl = Wlo + ((size_t)(matbase + 0) * 16384);
    const unsigned short* hpr = Whi + ((size_t)(matbase + 1) * 16384);
    const unsigned short* lpr = Wlo + ((size_t)(matbase + 1) * 16384);

    int tid = threadIdx.x;
    int w   = tid >> 6;
    int l   = tid & 63;
    int m15 = l & 15, g = l >> 4;
    int rowbase = blockIdx.x * 64 + w * 16;

    f32x4 accl[8], accr[8];
    #pragma unroll
    for (int nf = 0; nf < 8; ++nf) {
        accl[nf] = (f32x4){0.f, 0.f, 0.f, 0.f};
        accr[nf] = (f32x4){0.f, 0.f, 0.f, 0.f};
    }

    #pragma unroll
    for (int kb = 0; kb < 4; ++kb) {
        int arow = rowbase + m15;
        float4 x0 = make_float4(0.f, 0.f, 0.f, 0.f), x1 = x0;
        if (arow < nrows) {
            const float* xp = &X[(size_t)arow * 128 + kb * 32 + g * 8];
            x0 = *(const float4*)xp;
            x1 = *(const float4*)(xp + 4);
        }
        float xv[8] = {x0.x, x0.y, x0.z, x0.w, x1.x, x1.y, x1.z, x1.w};
        bf16x8 ahi, alo;
        #pragma unroll
        for (int j = 0; j < 8; ++j) {
            unsigned short h = f2bf_rne(xv[j]);
            ahi[j] = (short)h;
            alo[j] = (short)f2bf_rne(xv[j] - bf2f(h));
        }
        #pragma unroll
        for (int nf = 0; nf < 8; ++nf) {
            size_t off = (((size_t)kb * 8 + nf) * 64 + l) * 8;
            bf16x8 bhl = *(const bf16x8*)&hpl[off];
            bf16x8 bll = *(const bf16x8*)&lpl[off];
            bf16x8 bhr = *(const bf16x8*)&hpr[off];
            bf16x8 blr = *(const bf16x8*)&lpr[off];
            accl[nf] = __builtin_amdgcn_mfma_f32_16x16x32_bf16(ahi, bhl, accl[nf], 0, 0, 0);
            accl[nf] = __builtin_amdgcn_mfma_f32_16x16x32_bf16(ahi, bll, accl[nf], 0, 0, 0);
            accl[nf] = __builtin_amdgcn_mfma_f32_16x16x32_bf16(alo, bhl, accl[nf], 0, 0, 0);
            accr[nf] = __builtin_amdgcn_mfma_f32_16x16x32_bf16(ahi, bhr, accr[nf], 0, 0, 0);
            accr[nf] = __builtin_amdgcn_mfma_f32_16x16x32_bf16(ahi, blr, accr[nf], 0, 0, 0);
            accr[nf] = __builtin_amdgcn_mfma_f32_16x16x32_bf16(alo, bhr, accr[nf], 0, 0, 0);
        }
    }

    // biases for this lane's 8 columns (col = nf*16 + m15)
    float vbl[8], vbr[8];
    #pragma unroll
    for (int nf = 0; nf < 8; ++nf) {
        vbl[nf] = bl[nf * 16 + m15];
        vbr[nf] = br[nf * 16 + m15];
    }

    // packed 4B stores: pair (2a, 2a+1) -> position a*32 + m15*2
    #pragma unroll
    for (int a = 0; a < 4; ++a) {
        #pragma unroll
        for (int r = 0; r < 4; ++r) {
            int row = rowbase + g * 4 + r;
            if (row >= nrows) continue;
            size_t off = (size_t)row * 128 + a * 32 + m15 * 2;
            half2v pl, pr;
            pl[0] = (_Float16)(accl[2 * a][r]     + vbl[2 * a]);
            pl[1] = (_Float16)(accl[2 * a + 1][r] + vbl[2 * a + 1]);
            pr[0] = (_Float16)(accr[2 * a][r]     + vbr[2 * a]);
            pr[1] = (_Float16)(accr[2 * a + 1][r] + vbr[2 * a + 1]);
            *(half2v*)&xlh[off] = pl;
            *(half2v*)&xrh[off] = pr;
        }
    }
}

// ---------------------------------------------------------------------------
// Fused GATv2 aggregation — per-lane-per-head layout: lane gl holds 8
// channels of ONE head (lanes 0-7: head0, 8-15: head1). One dot + one
// rowsum8 (3 DPP) + one exp per edge. 4 groups x 16 lanes, no-max softmax,
// depth-2 rotated prefetch. Optional fused output projection.
// ---------------------------------------------------------------------------
__global__ __launch_bounds__(256) void gat_aggregate(
        const _Float16* __restrict__ xlh, const _Float16* __restrict__ xrh,
        const int* __restrict__ rowptr, const int* __restrict__ esrc,
        const float* __restrict__ att, const float* __restrict__ bias,
        float* __restrict__ hout, int n, int do_relu,
        const float* __restrict__ Wout, const float* __restrict__ bout,
        float* __restrict__ out4) {
    int node = (int)((blockIdx.x * blockDim.x + threadIdx.x) >> 6);
    int lane = threadIdx.x & 63;
    if (node >= n) return;
    int g    = lane >> 4;
    int gl   = lane & 15;
    int pos0 = gl * 8;

    // per-lane att (permuted) and xr
    half8 xr8 = *(const half8*)&xrh[(size_t)node * 128 + pos0];
    float xrf[8], atp[8], atn[8];
    #pragma unroll
    for (int i = 0; i < 8; ++i) {
        float a = att[colOf(pos0 + i)];
        atp[i] = a;
        atn[i] = NEG * a;
        xrf[i] = (float)xr8[i];
    }

    float s = 0.f;
    float acc[8];
    #pragma unroll
    for (int i = 0; i < 8; ++i) acc[i] = 0.f;

    int pbeg = rowptr[node], pend = rowptr[node + 1];
    int p = pbeg + g;
    bool v0 = p < pend;
    bool v1 = p + 4 < pend;
    half8 r0 = (half8)(_Float16)0.f, r1 = r0;
    if (v0) r0 = *(const half8*)&xlh[(size_t)esrc[p] * 128 + pos0];
    if (v1) r1 = *(const half8*)&xlh[(size_t)esrc[p + 4] * 128 + pos0];

    while (v0) {
        bool v2 = p + 8 < pend;              // uniform within 16-lane group
        half8 r2 = (half8)(_Float16)0.f;
        if (v2) r2 = *(const half8*)&xlh[(size_t)esrc[p + 8] * 128 + pos0];

        float av[8], t = 0.f;
        #pragma unroll
        for (int i = 0; i < 8; ++i) {
            av[i] = (float)r0[i];
            float v = av[i] + xrf[i];
            t += v * (v > 0.f ? atp[i] : atn[i]);
        }
        t = rowsum8(t);                      // per-head sum (8 lanes)
        float pp = __expf(fminf(t, 80.f));
        s += pp;
        #pragma unroll
        for (int i = 0; i < 8; ++i) acc[i] += pp * av[i];

        r0 = r1; r1 = r2; v0 = v1; v1 = v2; p += 4;
    }

    // merge the 4 group states (xor 16 then 32) — halves stay separate
    #pragma unroll
    for (int off = 16; off <= 32; off <<= 1) {
        s += __shfl_xor(s, off, 64);
        #pragma unroll
        for (int i = 0; i < 8; ++i) acc[i] += __shfl_xor(acc[i], off, 64);
    }

    float inv = 1.f / s;     // lanes 0-7: head0 denom; 8-15: head1 denom

    if (out4) {
        float o[8];
        #pragma unroll
        for (int i = 0; i < 8; ++i) {
            o[i] = acc[i] * inv + bias[colOf(pos0 + i)];
            if (do_relu) o[i] = fmaxf(o[i], 0.f);
        }
        float p0 = 0.f, p1 = 0.f, p2 = 0.f, p3 = 0.f;
        #pragma unroll
        for (int i = 0; i < 8; ++i) {
            float4 wv = *(const float4*)&Wout[colOf(pos0 + i) * 4];
            p0 += o[i] * wv.x; p1 += o[i] * wv.y;
            p2 += o[i] * wv.z; p3 += o[i] * wv.w;
        }
        p0 = rowsum16(p0); p1 = rowsum16(p1);
        p2 = rowsum16(p2); p3 = rowsum16(p3);
        if (lane == 0) {
            float4 ov = make_float4(p0 + bout[0], p1 + bout[1],
                                    p2 + bout[2], p3 + bout[3]);
            *(float4*)&out4[(size_t)node * 4] = ov;
        }
        return;
    }

    if (g == 0) {
        float o[8];
        #pragma unroll
        for (int i = 0; i < 8; ++i) {
            o[i] = acc[i] * inv + bias[colOf(pos0 + i)];
            if (do_relu) o[i] = fmaxf(o[i], 0.f);
        }
        float4 o0 = make_float4(o[0], o[1], o[2], o[3]);
        float4 o1 = make_float4(o[4], o[5], o[6], o[7]);
        *(float4*)&hout[(size_t)node * 128 + pos0]     = o0;
        *(float4*)&hout[(size_t)node * 128 + pos0 + 4] = o1;
    }
}

// ---------------------------------------------------------------------------
extern "C" void kernel_launch(void* const* d_in, const int* in_sizes, int n_in,
                              void* d_out, int out_size, void* d_ws,
                              size_t ws_size, hipStream_t stream) {
    // setup_inputs order:
    //  0:x 1:edge_index 2:W1l 3:b1l 4:W1r 5:b1r 6:att1 7:bias1
    //  8:W2l 9:b2l 10:W2r 11:b2r 12:att2 13:bias2
    // 14:W3l 15:b3l 16:W3r 17:b3r 18:att3 19:bias3 20:Wout 21:bout
    const float* x    = (const float*)d_in[0];
    const int*   ei   = (const int*)  d_in[1];
    const float* W1l  = (const float*)d_in[2];
    const float* b1l  = (const float*)d_in[3];
    const float* W1r  = (const float*)d_in[4];
    const float* b1r  = (const float*)d_in[5];
    const float* att1 = (const float*)d_in[6];
    const float* bias1= (const float*)d_in[7];
    const float* W2l  = (const float*)d_in[8];
    const float* b2l  = (const float*)d_in[9];
    const float* W2r  = (const float*)d_in[10];
    const float* b2r  = (const float*)d_in[11];
    const float* att2 = (const float*)d_in[12];
    const float* bias2= (const float*)d_in[13];
    const float* W3l  = (const float*)d_in[14];
    const float* b3l  = (const float*)d_in[15];
    const float* W3r  = (const float*)d_in[16];
    const float* b3r  = (const float*)d_in[17];
    const float* att3 = (const float*)d_in[18];
    const float* bias3= (const float*)d_in[19];
    const float* Wout = (const float*)d_in[20];
    const float* bout = (const float*)d_in[21];

    int N    = in_sizes[0] / DIN;
    int E    = in_sizes[1] / 2;
    int Etot = E + N;

    char* base = (char*)d_ws;
    float* h = (float*)base;              base += (size_t)N * HC * 4;
    _Float16* xlh = (_Float16*)base;      base += (size_t)N * HC * 2;
    _Float16* xrh = (_Float16*)base;      base += (size_t)N * HC * 2;
    unsigned short* whi = (unsigned short*)base;  base += 6 * 16384 * 2;
    unsigned short* wlo = (unsigned short*)base;  base += 6 * 16384 * 2;
    int* esrc   = (int*)base;             base += (size_t)Etot * 4;
    int* rowptr = (int*)base;             base += (size_t)(((N + 1) + 3) & ~3) * 4;
    int* cursor = (int*)base;             base += (size_t)N * 4;
    int* counts = (int*)base;

    hipMemsetAsync(counts, 0, (size_t)N * sizeof(int), stream);
    hist_kernel<<<(Etot + 255) / 256, 256, 0, stream>>>(ei, E, N, counts);
    scan_kernel<<<1, 1024, 0, stream>>>(counts, rowptr, cursor, N);
    scatter_kernel<<<(Etot + 255) / 256, 256, 0, stream>>>(ei, E, N, cursor, esrc);
    prep_w<<<dim3(8, 6), 256, 0, stream>>>(W1l, W1r, W2l, W2r, W3l, W3r, whi, wlo);

    int gemm_grid = (N + 63) / 64;
    int agg_grid  = (N + 3) / 4;

    gemm_mfma_dual<<<gemm_grid, 256, 0, stream>>>(x, whi, wlo, 0, b1l, b1r, xlh, xrh, N);
    gat_aggregate<<<agg_grid, 256, 0, stream>>>(xlh, xrh, rowptr, esrc, att1, bias1,
                                                h, N, 1, nullptr, nullptr, nullptr);
    gemm_mfma_dual<<<gemm_grid, 256, 0, stream>>>(h, whi, wlo, 2, b2l, b2r, xlh, xrh, N);
    gat_aggregate<<<agg_grid, 256, 0, stream>>>(xlh, xrh, rowptr, esrc, att2, bias2,
                                                h, N, 1, nullptr, nullptr, nullptr);
    gemm_mfma_dual<<<gemm_grid, 256, 0, stream>>>(h, whi, wlo, 4, b3l, b3r, xlh, xrh, N);
    // layer 3: fused relu + output projection, h never materialized
    gat_aggregate<<<agg_grid, 256, 0, stream>>>(xlh, xrh, rowptr, esrc, att3, bias3,
                                                nullptr, N, 1, Wout, bout,
                                                (float*)d_out);
}

// Round 14
// 348.006 us; speedup vs baseline: 1.1272x; 1.0387x over previous
//
#include <hip/hip_runtime.h>
#include <math.h>

#define DIN  128
#define HC   128
#define NEG  0.2f

typedef __attribute__((ext_vector_type(8))) short bf16x8;
typedef __attribute__((ext_vector_type(4))) float f32x4;
typedef __attribute__((ext_vector_type(8))) _Float16 half8;
typedef __attribute__((ext_vector_type(2))) _Float16 half2v;

__device__ __forceinline__ unsigned short f2bf_rne(float x) {
    unsigned u = __float_as_uint(x);
    unsigned r = u + 0x7FFFu + ((u >> 16) & 1u);
    return (unsigned short)(r >> 16);
}
__device__ __forceinline__ float bf2f(unsigned short h) {
    return __uint_as_float(((unsigned)h) << 16);
}

// stored position p (0..127)  ->  original channel column
__device__ __forceinline__ int colOf(int p) {
    return ((p >> 5) * 2 + (p & 1)) * 16 + ((p & 31) >> 1);
}

// DPP butterfly adds (pure VALU)
template <int CTRL>
__device__ __forceinline__ float dpp_xadd(float x) {
    int r = __builtin_amdgcn_update_dpp(0, __float_as_int(x), CTRL, 0xF, 0xF, true);
    return x + __int_as_float(r);
}
__device__ __forceinline__ float rowsum8(float x) {   // sum within 8-lane half-row
    x = dpp_xadd<0xB1>(x);   // lane ^ 1
    x = dpp_xadd<0x4E>(x);   // lane ^ 2
    x = dpp_xadd<0x141>(x);  // half-row mirror (lane ^ 7 within 8)
    return x;
}
__device__ __forceinline__ float rowsum16(float x) {
    x = dpp_xadd<0xB1>(x);
    x = dpp_xadd<0x4E>(x);
    x = dpp_xadd<0x141>(x);
    x = dpp_xadd<0x140>(x);  // row mirror (lane ^ 15)
    return x;
}

// ---------------------------------------------------------------------------
// CSR build
// ---------------------------------------------------------------------------
__global__ void hist_kernel(const int* __restrict__ ei, int E, int N,
                            int* __restrict__ counts) {
    int i = blockIdx.x * blockDim.x + threadIdx.x;
    int Etot = E + N;
    if (i >= Etot) return;
    int dst = (i < E) ? ei[E + i] : (i - E);
    if (dst < 0 || dst >= N) return;
    atomicAdd(&counts[dst], 1);
}

__global__ void scan_kernel(const int* __restrict__ counts,
                            int* __restrict__ rowptr,
                            int* __restrict__ cursor, int n) {
    __shared__ int wsum[16];
    int tid  = threadIdx.x;          // 1024 threads
    int lane = tid & 63, wid = tid >> 6;
    int running = 0;
    for (int base = 0; base < n; base += 4096) {
        int i = base + tid * 4;
        int4 v = make_int4(0, 0, 0, 0);
        if (i < n) v = *(const int4*)&counts[i];   // n % 4 == 0
        int ssum = v.x + v.y + v.z + v.w;
        int x = ssum;
        #pragma unroll
        for (int off = 1; off < 64; off <<= 1) {
            int y = __shfl_up(x, off, 64);
            if (lane >= off) x += y;
        }
        if (lane == 63) wsum[wid] = x;
        __syncthreads();
        if (tid < 16) {
            int w = wsum[tid];
            #pragma unroll
            for (int off = 1; off < 16; off <<= 1) {
                int y = __shfl_up(w, off, 64);
                if (tid >= off) w += y;
            }
            wsum[tid] = w;
        }
        __syncthreads();
        int excl = running + (wid ? wsum[wid - 1] : 0) + (x - ssum);
        if (i < n) {
            int4 r;
            r.x = excl;
            r.y = r.x + v.x;
            r.z = r.y + v.y;
            r.w = r.z + v.z;
            *(int4*)&rowptr[i] = r;
            *(int4*)&cursor[i] = r;
        }
        running += wsum[15];
        __syncthreads();
    }
    if (tid == 0) rowptr[n] = running;
}

__global__ void scatter_kernel(const int* __restrict__ ei, int E, int N,
                               int* __restrict__ cursor,
                               int* __restrict__ esrc) {
    int i = blockIdx.x * blockDim.x + threadIdx.x;
    int Etot = E + N;
    if (i >= Etot) return;
    int src = (i < E) ? ei[i]     : (i - E);
    int dst = (i < E) ? ei[E + i] : (i - E);
    if (dst < 0 || dst >= N || src < 0 || src >= N) return;
    int pos = atomicAdd(&cursor[dst], 1);
    esrc[pos] = src;
}

// ---------------------------------------------------------------------------
// W prep: split each 128x128 W into bf16 hi/lo, packed in MFMA B-fragment
// order. For layers 2/3 (m>=2) the k index refers to the PERMUTED h layout,
// so the W row is colOf(k).
// ---------------------------------------------------------------------------
__global__ __launch_bounds__(256) void prep_w(
        const float* __restrict__ W1l, const float* __restrict__ W1r,
        const float* __restrict__ W2l, const float* __restrict__ W2r,
        const float* __restrict__ W3l, const float* __restrict__ W3r,
        unsigned short* __restrict__ hi, unsigned short* __restrict__ lo) {
    int m = blockIdx.y;
    const float* W = (m == 0) ? W1l : (m == 1) ? W1r : (m == 2) ? W2l
                   : (m == 3) ? W2r : (m == 4) ? W3l : W3r;
    int t = blockIdx.x * 256 + threadIdx.x;    // 0..2047 (grid.x = 8)
    int kb = t >> 9, nf = (t >> 6) & 7, l = t & 63;
    int col = nf * 16 + (l & 15);
    int k0  = kb * 32 + (l >> 4) * 8;
    size_t ob = ((size_t)m * 2048 + t) * 8;
    #pragma unroll
    for (int j = 0; j < 8; ++j) {
        int k = k0 + j;
        int krow = (m >= 2) ? colOf(k) : k;
        float v = W[(size_t)krow * 128 + col];
        unsigned short h = f2bf_rne(v);
        hi[ob + j] = h;
        lo[ob + j] = f2bf_rne(v - bf2f(h));
    }
}

// ---------------------------------------------------------------------------
// Dual MFMA GEMM (split-bf16, 3 terms), OCCUPANCY-ORIENTED SPLIT:
// block = 4 waves over a 32-row tile; wave pair (w>>1) owns a 16-row MFMA
// slice, (w&1) selects nf half {0..3} or {4..7}. Per-wave acc = 32 VGPR,
// grid = ceil(N/32) (2x blocks, half VGPR vs round-13) -> TLP hides L2
// W-load latency. Outputs stored FP16 at permuted position
// newpos(col) = (nf>>1)*32 + m15*2 + (nf&1) as packed half2 (coalesced 64B).
// ---------------------------------------------------------------------------
__global__ __launch_bounds__(256) void gemm_mfma_dual(
        const float* __restrict__ X,
        const unsigned short* __restrict__ Whi,
        const unsigned short* __restrict__ Wlo, int matbase,
        const float* __restrict__ bl, const float* __restrict__ br,
        _Float16* __restrict__ xlh, _Float16* __restrict__ xrh, int nrows) {
    const unsigned short* hpl = Whi + ((size_t)(matbase + 0) * 16384);
    const unsigned short* lpl = Wlo + ((size_t)(matbase + 0) * 16384);
    const unsigned short* hpr = Whi + ((size_t)(matbase + 1) * 16384);
    const unsigned short* lpr = Wlo + ((size_t)(matbase + 1) * 16384);

    int tid = threadIdx.x;
    int w   = tid >> 6;
    int l   = tid & 63;
    int m15 = l & 15, g = l >> 4;
    int rowbase = blockIdx.x * 32 + (w >> 1) * 16;
    int nfb     = (w & 1) * 4;           // this wave's nf half

    f32x4 accl[4], accr[4];
    #pragma unroll
    for (int i = 0; i < 4; ++i) {
        accl[i] = (f32x4){0.f, 0.f, 0.f, 0.f};
        accr[i] = (f32x4){0.f, 0.f, 0.f, 0.f};
    }

    #pragma unroll
    for (int kb = 0; kb < 4; ++kb) {
        int arow = rowbase + m15;
        float4 x0 = make_float4(0.f, 0.f, 0.f, 0.f), x1 = x0;
        if (arow < nrows) {
            const float* xp = &X[(size_t)arow * 128 + kb * 32 + g * 8];
            x0 = *(const float4*)xp;
            x1 = *(const float4*)(xp + 4);
        }
        float xv[8] = {x0.x, x0.y, x0.z, x0.w, x1.x, x1.y, x1.z, x1.w};
        bf16x8 ahi, alo;
        #pragma unroll
        for (int j = 0; j < 8; ++j) {
            unsigned short h = f2bf_rne(xv[j]);
            ahi[j] = (short)h;
            alo[j] = (short)f2bf_rne(xv[j] - bf2f(h));
        }
        #pragma unroll
        for (int nfi = 0; nfi < 4; ++nfi) {
            int nf = nfb + nfi;
            size_t off = (((size_t)kb * 8 + nf) * 64 + l) * 8;
            bf16x8 bhl = *(const bf16x8*)&hpl[off];
            bf16x8 bll = *(const bf16x8*)&lpl[off];
            bf16x8 bhr = *(const bf16x8*)&hpr[off];
            bf16x8 blr = *(const bf16x8*)&lpr[off];
            accl[nfi] = __builtin_amdgcn_mfma_f32_16x16x32_bf16(ahi, bhl, accl[nfi], 0, 0, 0);
            accl[nfi] = __builtin_amdgcn_mfma_f32_16x16x32_bf16(ahi, bll, accl[nfi], 0, 0, 0);
            accl[nfi] = __builtin_amdgcn_mfma_f32_16x16x32_bf16(alo, bhl, accl[nfi], 0, 0, 0);
            accr[nfi] = __builtin_amdgcn_mfma_f32_16x16x32_bf16(ahi, bhr, accr[nfi], 0, 0, 0);
            accr[nfi] = __builtin_amdgcn_mfma_f32_16x16x32_bf16(ahi, blr, accr[nfi], 0, 0, 0);
            accr[nfi] = __builtin_amdgcn_mfma_f32_16x16x32_bf16(alo, bhr, accr[nfi], 0, 0, 0);
        }
    }

    // biases for this wave's 4 columns slices (col = (nfb+nfi)*16 + m15)
    float vbl[4], vbr[4];
    #pragma unroll
    for (int nfi = 0; nfi < 4; ++nfi) {
        vbl[nfi] = bl[(nfb + nfi) * 16 + m15];
        vbr[nfi] = br[(nfb + nfi) * 16 + m15];
    }

    // packed 4B stores: fragment pair (2a2, 2a2+1) -> position a*32 + m15*2,
    // a = nfb/2 + a2 (this wave covers positions [a*32, a*32+32))
    #pragma unroll
    for (int a2 = 0; a2 < 2; ++a2) {
        int a = (nfb >> 1) + a2;
        #pragma unroll
        for (int r = 0; r < 4; ++r) {
            int row = rowbase + g * 4 + r;
            if (row >= nrows) continue;
            size_t off = (size_t)row * 128 + a * 32 + m15 * 2;
            half2v pl, pr;
            pl[0] = (_Float16)(accl[2 * a2][r]     + vbl[2 * a2]);
            pl[1] = (_Float16)(accl[2 * a2 + 1][r] + vbl[2 * a2 + 1]);
            pr[0] = (_Float16)(accr[2 * a2][r]     + vbr[2 * a2]);
            pr[1] = (_Float16)(accr[2 * a2 + 1][r] + vbr[2 * a2 + 1]);
            *(half2v*)&xlh[off] = pl;
            *(half2v*)&xrh[off] = pr;
        }
    }
}

// ---------------------------------------------------------------------------
// Fused GATv2 aggregation — per-lane-per-head layout: lane gl holds 8
// channels of ONE head (lanes 0-7: head0, 8-15: head1). One dot + one
// rowsum8 (3 DPP) + one exp per edge. 4 groups x 16 lanes, no-max softmax,
// depth-2 rotated prefetch. Optional fused output projection.
// ---------------------------------------------------------------------------
__global__ __launch_bounds__(256) void gat_aggregate(
        const _Float16* __restrict__ xlh, const _Float16* __restrict__ xrh,
        const int* __restrict__ rowptr, const int* __restrict__ esrc,
        const float* __restrict__ att, const float* __restrict__ bias,
        float* __restrict__ hout, int n, int do_relu,
        const float* __restrict__ Wout, const float* __restrict__ bout,
        float* __restrict__ out4) {
    int node = (int)((blockIdx.x * blockDim.x + threadIdx.x) >> 6);
    int lane = threadIdx.x & 63;
    if (node >= n) return;
    int g    = lane >> 4;
    int gl   = lane & 15;
    int pos0 = gl * 8;

    // per-lane att (permuted) and xr
    half8 xr8 = *(const half8*)&xrh[(size_t)node * 128 + pos0];
    float xrf[8], atp[8], atn[8];
    #pragma unroll
    for (int i = 0; i < 8; ++i) {
        float a = att[colOf(pos0 + i)];
        atp[i] = a;
        atn[i] = NEG * a;
        xrf[i] = (float)xr8[i];
    }

    float s = 0.f;
    float acc[8];
    #pragma unroll
    for (int i = 0; i < 8; ++i) acc[i] = 0.f;

    int pbeg = rowptr[node], pend = rowptr[node + 1];
    int p = pbeg + g;
    bool v0 = p < pend;
    bool v1 = p + 4 < pend;
    half8 r0 = (half8)(_Float16)0.f, r1 = r0;
    if (v0) r0 = *(const half8*)&xlh[(size_t)esrc[p] * 128 + pos0];
    if (v1) r1 = *(const half8*)&xlh[(size_t)esrc[p + 4] * 128 + pos0];

    while (v0) {
        bool v2 = p + 8 < pend;              // uniform within 16-lane group
        half8 r2 = (half8)(_Float16)0.f;
        if (v2) r2 = *(const half8*)&xlh[(size_t)esrc[p + 8] * 128 + pos0];

        float av[8], t = 0.f;
        #pragma unroll
        for (int i = 0; i < 8; ++i) {
            av[i] = (float)r0[i];
            float v = av[i] + xrf[i];
            t += v * (v > 0.f ? atp[i] : atn[i]);
        }
        t = rowsum8(t);                      // per-head sum (8 lanes)
        float pp = __expf(fminf(t, 80.f));
        s += pp;
        #pragma unroll
        for (int i = 0; i < 8; ++i) acc[i] += pp * av[i];

        r0 = r1; r1 = r2; v0 = v1; v1 = v2; p += 4;
    }

    // merge the 4 group states (xor 16 then 32) — halves stay separate
    #pragma unroll
    for (int off = 16; off <= 32; off <<= 1) {
        s += __shfl_xor(s, off, 64);
        #pragma unroll
        for (int i = 0; i < 8; ++i) acc[i] += __shfl_xor(acc[i], off, 64);
    }

    float inv = 1.f / s;     // lanes 0-7: head0 denom; 8-15: head1 denom

    if (out4) {
        float o[8];
        #pragma unroll
        for (int i = 0; i < 8; ++i) {
            o[i] = acc[i] * inv + bias[colOf(pos0 + i)];
            if (do_relu) o[i] = fmaxf(o[i], 0.f);
        }
        float p0 = 0.f, p1 = 0.f, p2 = 0.f, p3 = 0.f;
        #pragma unroll
        for (int i = 0; i < 8; ++i) {
            float4 wv = *(const float4*)&Wout[colOf(pos0 + i) * 4];
            p0 += o[i] * wv.x; p1 += o[i] * wv.y;
            p2 += o[i] * wv.z; p3 += o[i] * wv.w;
        }
        p0 = rowsum16(p0); p1 = rowsum16(p1);
        p2 = rowsum16(p2); p3 = rowsum16(p3);
        if (lane == 0) {
            float4 ov = make_float4(p0 + bout[0], p1 + bout[1],
                                    p2 + bout[2], p3 + bout[3]);
            *(float4*)&out4[(size_t)node * 4] = ov;
        }
        return;
    }

    if (g == 0) {
        float o[8];
        #pragma unroll
        for (int i = 0; i < 8; ++i) {
            o[i] = acc[i] * inv + bias[colOf(pos0 + i)];
            if (do_relu) o[i] = fmaxf(o[i], 0.f);
        }
        float4 o0 = make_float4(o[0], o[1], o[2], o[3]);
        float4 o1 = make_float4(o[4], o[5], o[6], o[7]);
        *(float4*)&hout[(size_t)node * 128 + pos0]     = o0;
        *(float4*)&hout[(size_t)node * 128 + pos0 + 4] = o1;
    }
}

// ---------------------------------------------------------------------------
extern "C" void kernel_launch(void* const* d_in, const int* in_sizes, int n_in,
                              void* d_out, int out_size, void* d_ws,
                              size_t ws_size, hipStream_t stream) {
    // setup_inputs order:
    //  0:x 1:edge_index 2:W1l 3:b1l 4:W1r 5:b1r 6:att1 7:bias1
    //  8:W2l 9:b2l 10:W2r 11:b2r 12:att2 13:bias2
    // 14:W3l 15:b3l 16:W3r 17:b3r 18:att3 19:bias3 20:Wout 21:bout
    const float* x    = (const float*)d_in[0];
    const int*   ei   = (const int*)  d_in[1];
    const float* W1l  = (const float*)d_in[2];
    const float* b1l  = (const float*)d_in[3];
    const float* W1r  = (const float*)d_in[4];
    const float* b1r  = (const float*)d_in[5];
    const float* att1 = (const float*)d_in[6];
    const float* bias1= (const float*)d_in[7];
    const float* W2l  = (const float*)d_in[8];
    const float* b2l  = (const float*)d_in[9];
    const float* W2r  = (const float*)d_in[10];
    const float* b2r  = (const float*)d_in[11];
    const float* att2 = (const float*)d_in[12];
    const float* bias2= (const float*)d_in[13];
    const float* W3l  = (const float*)d_in[14];
    const float* b3l  = (const float*)d_in[15];
    const float* W3r  = (const float*)d_in[16];
    const float* b3r  = (const float*)d_in[17];
    const float* att3 = (const float*)d_in[18];
    const float* bias3= (const float*)d_in[19];
    const float* Wout = (const float*)d_in[20];
    const float* bout = (const float*)d_in[21];

    int N    = in_sizes[0] / DIN;
    int E    = in_sizes[1] / 2;
    int Etot = E + N;

    char* base = (char*)d_ws;
    float* h = (float*)base;              base += (size_t)N * HC * 4;
    _Float16* xlh = (_Float16*)base;      base += (size_t)N * HC * 2;
    _Float16* xrh = (_Float16*)base;      base += (size_t)N * HC * 2;
    unsigned short* whi = (unsigned short*)base;  base += 6 * 16384 * 2;
    unsigned short* wlo = (unsigned short*)base;  base += 6 * 16384 * 2;
    int* esrc   = (int*)base;             base += (size_t)Etot * 4;
    int* rowptr = (int*)base;             base += (size_t)(((N + 1) + 3) & ~3) * 4;
    int* cursor = (int*)base;             base += (size_t)N * 4;
    int* counts = (int*)base;

    hipMemsetAsync(counts, 0, (size_t)N * sizeof(int), stream);
    hist_kernel<<<(Etot + 255) / 256, 256, 0, stream>>>(ei, E, N, counts);
    scan_kernel<<<1, 1024, 0, stream>>>(counts, rowptr, cursor, N);
    scatter_kernel<<<(Etot + 255) / 256, 256, 0, stream>>>(ei, E, N, cursor, esrc);
    prep_w<<<dim3(8, 6), 256, 0, stream>>>(W1l, W1r, W2l, W2r, W3l, W3r, whi, wlo);

    int gemm_grid = (N + 31) / 32;
    int agg_grid  = (N + 3) / 4;

    gemm_mfma_dual<<<gemm_grid, 256, 0, stream>>>(x, whi, wlo, 0, b1l, b1r, xlh, xrh, N);
    gat_aggregate<<<agg_grid, 256, 0, stream>>>(xlh, xrh, rowptr, esrc, att1, bias1,
                                                h, N, 1, nullptr, nullptr, nullptr);
    gemm_mfma_dual<<<gemm_grid, 256, 0, stream>>>(h, whi, wlo, 2, b2l, b2r, xlh, xrh, N);
    gat_aggregate<<<agg_grid, 256, 0, stream>>>(xlh, xrh, rowptr, esrc, att2, bias2,
                                                h, N, 1, nullptr, nullptr, nullptr);
    gemm_mfma_dual<<<gemm_grid, 256, 0, stream>>>(h, whi, wlo, 4, b3l, b3r, xlh, xrh, N);
    // layer 3: fused relu + output projection, h never materialized
    gat_aggregate<<<agg_grid, 256, 0, stream>>>(xlh, xrh, rowptr, esrc, att3, bias3,
                                                nullptr, N, 1, Wout, bout,
                                                (float*)d_out);
}

// Round 15
// 320.450 us; speedup vs baseline: 1.2242x; 1.0860x over previous
//
#include <hip/hip_runtime.h>
#include <math.h>

#define DIN  128
#define HC   128
#define NEG  0.2f

typedef __attribute__((ext_vector_type(4))) float f32x4;
typedef __attribute__((ext_vector_type(8))) _Float16 half8;
typedef __attribute__((ext_vector_type(2))) _Float16 half2v;

// stored position p (0..127)  ->  original channel column
__device__ __forceinline__ int colOf(int p) {
    return ((p >> 5) * 2 + (p & 1)) * 16 + ((p & 31) >> 1);
}

// DPP butterfly adds (pure VALU)
template <int CTRL>
__device__ __forceinline__ float dpp_xadd(float x) {
    int r = __builtin_amdgcn_update_dpp(0, __float_as_int(x), CTRL, 0xF, 0xF, true);
    return x + __int_as_float(r);
}
__device__ __forceinline__ float rowsum8(float x) {   // sum within 8-lane half-row
    x = dpp_xadd<0xB1>(x);   // lane ^ 1
    x = dpp_xadd<0x4E>(x);   // lane ^ 2
    x = dpp_xadd<0x141>(x);  // half-row mirror (lane ^ 7 within 8)
    return x;
}
__device__ __forceinline__ float rowsum16(float x) {
    x = dpp_xadd<0xB1>(x);
    x = dpp_xadd<0x4E>(x);
    x = dpp_xadd<0x141>(x);
    x = dpp_xadd<0x140>(x);  // row mirror (lane ^ 15)
    return x;
}

// ---------------------------------------------------------------------------
// CSR build
// ---------------------------------------------------------------------------
__global__ void hist_kernel(const int* __restrict__ ei, int E, int N,
                            int* __restrict__ counts) {
    int i = blockIdx.x * blockDim.x + threadIdx.x;
    int Etot = E + N;
    if (i >= Etot) return;
    int dst = (i < E) ? ei[E + i] : (i - E);
    if (dst < 0 || dst >= N) return;
    atomicAdd(&counts[dst], 1);
}

__global__ void scan_kernel(const int* __restrict__ counts,
                            int* __restrict__ rowptr,
                            int* __restrict__ cursor, int n) {
    __shared__ int wsum[16];
    int tid  = threadIdx.x;          // 1024 threads
    int lane = tid & 63, wid = tid >> 6;
    int running = 0;
    for (int base = 0; base < n; base += 4096) {
        int i = base + tid * 4;
        int4 v = make_int4(0, 0, 0, 0);
        if (i < n) v = *(const int4*)&counts[i];   // n % 4 == 0
        int ssum = v.x + v.y + v.z + v.w;
        int x = ssum;
        #pragma unroll
        for (int off = 1; off < 64; off <<= 1) {
            int y = __shfl_up(x, off, 64);
            if (lane >= off) x += y;
        }
        if (lane == 63) wsum[wid] = x;
        __syncthreads();
        if (tid < 16) {
            int w = wsum[tid];
            #pragma unroll
            for (int off = 1; off < 16; off <<= 1) {
                int y = __shfl_up(w, off, 64);
                if (tid >= off) w += y;
            }
            wsum[tid] = w;
        }
        __syncthreads();
        int excl = running + (wid ? wsum[wid - 1] : 0) + (x - ssum);
        if (i < n) {
            int4 r;
            r.x = excl;
            r.y = r.x + v.x;
            r.z = r.y + v.y;
            r.w = r.z + v.z;
            *(int4*)&rowptr[i] = r;
            *(int4*)&cursor[i] = r;
        }
        running += wsum[15];
        __syncthreads();
    }
    if (tid == 0) rowptr[n] = running;
}

__global__ void scatter_kernel(const int* __restrict__ ei, int E, int N,
                               int* __restrict__ cursor,
                               int* __restrict__ esrc) {
    int i = blockIdx.x * blockDim.x + threadIdx.x;
    int Etot = E + N;
    if (i >= Etot) return;
    int src = (i < E) ? ei[i]     : (i - E);
    int dst = (i < E) ? ei[E + i] : (i - E);
    if (dst < 0 || dst >= N || src < 0 || src >= N) return;
    int pos = atomicAdd(&cursor[dst], 1);
    esrc[pos] = src;
}

// ---------------------------------------------------------------------------
// W prep: pack each 128x128 W as SINGLE-fp16 MFMA B-fragments.
// slot (kb,nf,lane,j) = W[krow][nf*16 + (lane&15)], krow = colOf(k) for
// layers 2/3 (permuted h layout), k = kb*32 + (lane>>4)*8 + j.
// ---------------------------------------------------------------------------
__global__ __launch_bounds__(256) void prep_w16(
        const float* __restrict__ W1l, const float* __restrict__ W1r,
        const float* __restrict__ W2l, const float* __restrict__ W2r,
        const float* __restrict__ W3l, const float* __restrict__ W3r,
        _Float16* __restrict__ w16) {
    int m = blockIdx.y;
    const float* W = (m == 0) ? W1l : (m == 1) ? W1r : (m == 2) ? W2l
                   : (m == 3) ? W2r : (m == 4) ? W3l : W3r;
    int t = blockIdx.x * 256 + threadIdx.x;    // 0..2047 (grid.x = 8)
    int kb = t >> 9, nf = (t >> 6) & 7, l = t & 63;
    int col = nf * 16 + (l & 15);
    int k0  = kb * 32 + (l >> 4) * 8;
    size_t ob = ((size_t)m * 2048 + t) * 8;
    #pragma unroll
    for (int j = 0; j < 8; ++j) {
        int k = k0 + j;
        int krow = (m >= 2) ? colOf(k) : k;
        w16[ob + j] = (_Float16)W[(size_t)krow * 128 + col];
    }
}

// ---------------------------------------------------------------------------
// Dual fp16 MFMA GEMM — single-term (A fp16, W fp16; absmax headroom covers
// the 2^-11 W error). r14 occupancy split: block = 4 waves over a 32-row
// tile; wave pair (w>>1) owns a 16-row MFMA slice, (w&1) selects nf half.
// Per-wave: 32 MFMAs, 2 W streams. Outputs fp16 at permuted positions,
// packed half2 stores (coalesced 64B).
// Two variants: A from fp32 (layer 1) / A from fp16 permuted h (layers 2/3).
// ---------------------------------------------------------------------------
#define GEMM_BODY(A_LOAD)                                                     \
    const _Float16* hpl = W16 + ((size_t)(matbase + 0) * 16384);              \
    const _Float16* hpr = W16 + ((size_t)(matbase + 1) * 16384);              \
    int tid = threadIdx.x;                                                    \
    int w   = tid >> 6;                                                       \
    int l   = tid & 63;                                                       \
    int m15 = l & 15, g = l >> 4;                                             \
    int rowbase = blockIdx.x * 32 + (w >> 1) * 16;                            \
    int nfb     = (w & 1) * 4;                                                \
    f32x4 accl[4], accr[4];                                                   \
    _Pragma("unroll")                                                         \
    for (int i = 0; i < 4; ++i) {                                             \
        accl[i] = (f32x4){0.f, 0.f, 0.f, 0.f};                                \
        accr[i] = (f32x4){0.f, 0.f, 0.f, 0.f};                                \
    }                                                                         \
    _Pragma("unroll")                                                         \
    for (int kb = 0; kb < 4; ++kb) {                                          \
        int arow = rowbase + m15;                                             \
        half8 a16 = (half8)(_Float16)0.f;                                     \
        A_LOAD                                                                \
        _Pragma("unroll")                                                     \
        for (int nfi = 0; nfi < 4; ++nfi) {                                   \
            int nf = nfb + nfi;                                               \
            size_t off = (((size_t)kb * 8 + nf) * 64 + l) * 8;                \
            half8 b_l = *(const half8*)&hpl[off];                             \
            half8 b_r = *(const half8*)&hpr[off];                             \
            accl[nfi] = __builtin_amdgcn_mfma_f32_16x16x32_f16(a16, b_l, accl[nfi], 0, 0, 0); \
            accr[nfi] = __builtin_amdgcn_mfma_f32_16x16x32_f16(a16, b_r, accr[nfi], 0, 0, 0); \
        }                                                                     \
    }                                                                         \
    float vbl[4], vbr[4];                                                     \
    _Pragma("unroll")                                                         \
    for (int nfi = 0; nfi < 4; ++nfi) {                                       \
        vbl[nfi] = bl[(nfb + nfi) * 16 + m15];                                \
        vbr[nfi] = br[(nfb + nfi) * 16 + m15];                                \
    }                                                                         \
    _Pragma("unroll")                                                         \
    for (int a2 = 0; a2 < 2; ++a2) {                                          \
        int a = (nfb >> 1) + a2;                                              \
        _Pragma("unroll")                                                     \
        for (int r = 0; r < 4; ++r) {                                         \
            int row = rowbase + g * 4 + r;                                    \
            if (row >= nrows) continue;                                       \
            size_t off = (size_t)row * 128 + a * 32 + m15 * 2;                \
            half2v pl, pr;                                                    \
            pl[0] = (_Float16)(accl[2 * a2][r]     + vbl[2 * a2]);            \
            pl[1] = (_Float16)(accl[2 * a2 + 1][r] + vbl[2 * a2 + 1]);        \
            pr[0] = (_Float16)(accr[2 * a2][r]     + vbr[2 * a2]);            \
            pr[1] = (_Float16)(accr[2 * a2 + 1][r] + vbr[2 * a2 + 1]);        \
            *(half2v*)&xlh[off] = pl;                                         \
            *(half2v*)&xrh[off] = pr;                                         \
        }                                                                     \
    }

__global__ __launch_bounds__(256) void gemm_f16_from_f32(
        const float* __restrict__ X, const _Float16* __restrict__ W16,
        int matbase, const float* __restrict__ bl, const float* __restrict__ br,
        _Float16* __restrict__ xlh, _Float16* __restrict__ xrh, int nrows) {
    GEMM_BODY(
        if (arow < nrows) {
            const float* xp = &X[(size_t)arow * 128 + kb * 32 + g * 8];
            float4 x0 = *(const float4*)xp;
            float4 x1 = *(const float4*)(xp + 4);
            a16[0] = (_Float16)x0.x; a16[1] = (_Float16)x0.y;
            a16[2] = (_Float16)x0.z; a16[3] = (_Float16)x0.w;
            a16[4] = (_Float16)x1.x; a16[5] = (_Float16)x1.y;
            a16[6] = (_Float16)x1.z; a16[7] = (_Float16)x1.w;
        }
    )
}

__global__ __launch_bounds__(256) void gemm_f16_from_f16(
        const _Float16* __restrict__ X, const _Float16* __restrict__ W16,
        int matbase, const float* __restrict__ bl, const float* __restrict__ br,
        _Float16* __restrict__ xlh, _Float16* __restrict__ xrh, int nrows) {
    GEMM_BODY(
        if (arow < nrows)
            a16 = *(const half8*)&X[(size_t)arow * 128 + kb * 32 + g * 8];
    )
}

// ---------------------------------------------------------------------------
// Fused GATv2 aggregation — per-lane-per-head layout (lanes 0-7: head0,
// 8-15: head1). One dot + rowsum8 (3 DPP) + one exp per edge. 4 groups x 16
// lanes, no-max softmax, depth-2 rotated prefetch. h written fp16 (half8).
// Optional fused output projection (layer 3).
// ---------------------------------------------------------------------------
__global__ __launch_bounds__(256) void gat_aggregate(
        const _Float16* __restrict__ xlh, const _Float16* __restrict__ xrh,
        const int* __restrict__ rowptr, const int* __restrict__ esrc,
        const float* __restrict__ att, const float* __restrict__ bias,
        _Float16* __restrict__ hout, int n, int do_relu,
        const float* __restrict__ Wout, const float* __restrict__ bout,
        float* __restrict__ out4) {
    int node = (int)((blockIdx.x * blockDim.x + threadIdx.x) >> 6);
    int lane = threadIdx.x & 63;
    if (node >= n) return;
    int g    = lane >> 4;
    int gl   = lane & 15;
    int pos0 = gl * 8;

    // per-lane att (permuted) and xr
    half8 xr8 = *(const half8*)&xrh[(size_t)node * 128 + pos0];
    float xrf[8], atp[8], atn[8];
    #pragma unroll
    for (int i = 0; i < 8; ++i) {
        float a = att[colOf(pos0 + i)];
        atp[i] = a;
        atn[i] = NEG * a;
        xrf[i] = (float)xr8[i];
    }

    float s = 0.f;
    float acc[8];
    #pragma unroll
    for (int i = 0; i < 8; ++i) acc[i] = 0.f;

    int pbeg = rowptr[node], pend = rowptr[node + 1];
    int p = pbeg + g;
    bool v0 = p < pend;
    bool v1 = p + 4 < pend;
    half8 r0 = (half8)(_Float16)0.f, r1 = r0;
    if (v0) r0 = *(const half8*)&xlh[(size_t)esrc[p] * 128 + pos0];
    if (v1) r1 = *(const half8*)&xlh[(size_t)esrc[p + 4] * 128 + pos0];

    while (v0) {
        bool v2 = p + 8 < pend;              // uniform within 16-lane group
        half8 r2 = (half8)(_Float16)0.f;
        if (v2) r2 = *(const half8*)&xlh[(size_t)esrc[p + 8] * 128 + pos0];

        float av[8], t = 0.f;
        #pragma unroll
        for (int i = 0; i < 8; ++i) {
            av[i] = (float)r0[i];
            float v = av[i] + xrf[i];
            t += v * (v > 0.f ? atp[i] : atn[i]);
        }
        t = rowsum8(t);                      // per-head sum (8 lanes)
        float pp = __expf(fminf(t, 80.f));
        s += pp;
        #pragma unroll
        for (int i = 0; i < 8; ++i) acc[i] += pp * av[i];

        r0 = r1; r1 = r2; v0 = v1; v1 = v2; p += 4;
    }

    // merge the 4 group states (xor 16 then 32) — halves stay separate
    #pragma unroll
    for (int off = 16; off <= 32; off <<= 1) {
        s += __shfl_xor(s, off, 64);
        #pragma unroll
        for (int i = 0; i < 8; ++i) acc[i] += __shfl_xor(acc[i], off, 64);
    }

    float inv = 1.f / s;     // lanes 0-7: head0 denom; 8-15: head1 denom

    if (out4) {
        float o[8];
        #pragma unroll
        for (int i = 0; i < 8; ++i) {
            o[i] = acc[i] * inv + bias[colOf(pos0 + i)];
            if (do_relu) o[i] = fmaxf(o[i], 0.f);
        }
        float p0 = 0.f, p1 = 0.f, p2 = 0.f, p3 = 0.f;
        #pragma unroll
        for (int i = 0; i < 8; ++i) {
            float4 wv = *(const float4*)&Wout[colOf(pos0 + i) * 4];
            p0 += o[i] * wv.x; p1 += o[i] * wv.y;
            p2 += o[i] * wv.z; p3 += o[i] * wv.w;
        }
        p0 = rowsum16(p0); p1 = rowsum16(p1);
        p2 = rowsum16(p2); p3 = rowsum16(p3);
        if (lane == 0) {
            float4 ov = make_float4(p0 + bout[0], p1 + bout[1],
                                    p2 + bout[2], p3 + bout[3]);
            *(float4*)&out4[(size_t)node * 4] = ov;
        }
        return;
    }

    if (g == 0) {
        half8 oh;
        #pragma unroll
        for (int i = 0; i < 8; ++i) {
            float o = acc[i] * inv + bias[colOf(pos0 + i)];
            if (do_relu) o = fmaxf(o, 0.f);
            oh[i] = (_Float16)o;
        }
        *(half8*)&hout[(size_t)node * 128 + pos0] = oh;
    }
}

// ---------------------------------------------------------------------------
extern "C" void kernel_launch(void* const* d_in, const int* in_sizes, int n_in,
                              void* d_out, int out_size, void* d_ws,
                              size_t ws_size, hipStream_t stream) {
    // setup_inputs order:
    //  0:x 1:edge_index 2:W1l 3:b1l 4:W1r 5:b1r 6:att1 7:bias1
    //  8:W2l 9:b2l 10:W2r 11:b2r 12:att2 13:bias2
    // 14:W3l 15:b3l 16:W3r 17:b3r 18:att3 19:bias3 20:Wout 21:bout
    const float* x    = (const float*)d_in[0];
    const int*   ei   = (const int*)  d_in[1];
    const float* W1l  = (const float*)d_in[2];
    const float* b1l  = (const float*)d_in[3];
    const float* W1r  = (const float*)d_in[4];
    const float* b1r  = (const float*)d_in[5];
    const float* att1 = (const float*)d_in[6];
    const float* bias1= (const float*)d_in[7];
    const float* W2l  = (const float*)d_in[8];
    const float* b2l  = (const float*)d_in[9];
    const float* W2r  = (const float*)d_in[10];
    const float* b2r  = (const float*)d_in[11];
    const float* att2 = (const float*)d_in[12];
    const float* bias2= (const float*)d_in[13];
    const float* W3l  = (const float*)d_in[14];
    const float* b3l  = (const float*)d_in[15];
    const float* W3r  = (const float*)d_in[16];
    const float* b3r  = (const float*)d_in[17];
    const float* att3 = (const float*)d_in[18];
    const float* bias3= (const float*)d_in[19];
    const float* Wout = (const float*)d_in[20];
    const float* bout = (const float*)d_in[21];

    int N    = in_sizes[0] / DIN;
    int E    = in_sizes[1] / 2;
    int Etot = E + N;

    char* base = (char*)d_ws;
    _Float16* h16 = (_Float16*)base;      base += (size_t)N * HC * 2;
    _Float16* xlh = (_Float16*)base;      base += (size_t)N * HC * 2;
    _Float16* xrh = (_Float16*)base;      base += (size_t)N * HC * 2;
    _Float16* w16 = (_Float16*)base;      base += 6 * 16384 * 2;
    int* esrc   = (int*)base;             base += (size_t)Etot * 4;
    int* rowptr = (int*)base;             base += (size_t)(((N + 1) + 3) & ~3) * 4;
    int* cursor = (int*)base;             base += (size_t)N * 4;
    int* counts = (int*)base;

    hipMemsetAsync(counts, 0, (size_t)N * sizeof(int), stream);
    hist_kernel<<<(Etot + 255) / 256, 256, 0, stream>>>(ei, E, N, counts);
    scan_kernel<<<1, 1024, 0, stream>>>(counts, rowptr, cursor, N);
    scatter_kernel<<<(Etot + 255) / 256, 256, 0, stream>>>(ei, E, N, cursor, esrc);
    prep_w16<<<dim3(8, 6), 256, 0, stream>>>(W1l, W1r, W2l, W2r, W3l, W3r, w16);

    int gemm_grid = (N + 31) / 32;
    int agg_grid  = (N + 3) / 4;

    gemm_f16_from_f32<<<gemm_grid, 256, 0, stream>>>(x, w16, 0, b1l, b1r, xlh, xrh, N);
    gat_aggregate<<<agg_grid, 256, 0, stream>>>(xlh, xrh, rowptr, esrc, att1, bias1,
                                                h16, N, 1, nullptr, nullptr, nullptr);
    gemm_f16_from_f16<<<gemm_grid, 256, 0, stream>>>(h16, w16, 2, b2l, b2r, xlh, xrh, N);
    gat_aggregate<<<agg_grid, 256, 0, stream>>>(xlh, xrh, rowptr, esrc, att2, bias2,
                                                h16, N, 1, nullptr, nullptr, nullptr);
    gemm_f16_from_f16<<<gemm_grid, 256, 0, stream>>>(h16, w16, 4, b3l, b3r, xlh, xrh, N);
    // layer 3: fused relu + output projection, h never materialized
    gat_aggregate<<<agg_grid, 256, 0, stream>>>(xlh, xrh, rowptr, esrc, att3, bias3,
                                                nullptr, N, 1, Wout, bout,
                                                (float*)d_out);
}